// Round 1
// baseline (1520.799 us; speedup 1.0000x reference)
//
#include <hip/hip_runtime.h>
#include <hip/hip_bf16.h>

// Problem: B=2, T=2048, D=1024, H=16, hd=64
// out = ((K_score @ v) / sum(K_score)) @ Wout.T  with
// K_score = x_dot^2 / max(2.01 - 2*x_dot, 1e-6), x_dot = qn . kn (L2-normalized),
// causal (s <= t).

#define T_SEQ 2048
#define D_MODEL 1024
#define N_HEADS 16
#define HD 64
#define BT 4096           // B*T
#define QKV_N 3072        // 3*D

// ---------------- GEMM: C[M,N] = A[M,K] * B[N,K]^T  (fp32) ----------------
#define GBM 64
#define GBN 64
#define GBK 16

__global__ __launch_bounds__(256) void gemm_abt(const float* __restrict__ A,
                                                const float* __restrict__ B,
                                                float* __restrict__ C,
                                                int M, int N, int K) {
    __shared__ float As[GBM][GBK + 1];
    __shared__ float Bs[GBN][GBK + 1];
    const int tid = threadIdx.x;
    const int bm = blockIdx.y * GBM;
    const int bn = blockIdx.x * GBN;
    const int tx = tid & 15;       // -> 4 columns
    const int ty = tid >> 4;       // -> 4 rows
    const int lrow = tid >> 2;     // 0..63 load row
    const int lk = (tid & 3) << 2; // 0,4,8,12 load k offset

    float acc[4][4] = {};

    for (int k0 = 0; k0 < K; k0 += GBK) {
        float4 av = *(const float4*)(A + (size_t)(bm + lrow) * K + k0 + lk);
        float4 bv = *(const float4*)(B + (size_t)(bn + lrow) * K + k0 + lk);
        As[lrow][lk + 0] = av.x; As[lrow][lk + 1] = av.y;
        As[lrow][lk + 2] = av.z; As[lrow][lk + 3] = av.w;
        Bs[lrow][lk + 0] = bv.x; Bs[lrow][lk + 1] = bv.y;
        Bs[lrow][lk + 2] = bv.z; Bs[lrow][lk + 3] = bv.w;
        __syncthreads();
#pragma unroll
        for (int kk = 0; kk < GBK; ++kk) {
            float a[4], b[4];
#pragma unroll
            for (int i = 0; i < 4; ++i) a[i] = As[ty * 4 + i][kk];
#pragma unroll
            for (int j = 0; j < 4; ++j) b[j] = Bs[tx * 4 + j][kk];
#pragma unroll
            for (int i = 0; i < 4; ++i)
#pragma unroll
                for (int j = 0; j < 4; ++j)
                    acc[i][j] = fmaf(a[i], b[j], acc[i][j]);
        }
        __syncthreads();
    }
#pragma unroll
    for (int i = 0; i < 4; ++i) {
        float4 o;
        o.x = acc[i][0]; o.y = acc[i][1]; o.z = acc[i][2]; o.w = acc[i][3];
        *(float4*)(C + (size_t)(bm + ty * 4 + i) * N + bn + tx * 4) = o;
    }
}

// ---------------- L2 normalize q,k rows in-place ----------------
// One 64-lane wave per (n, h, q|k) row of 64 elems. 4 waves / block.
__global__ __launch_bounds__(256) void l2norm_qk(float* __restrict__ qkv) {
    const int gid = blockIdx.x * 4 + (threadIdx.x >> 6);
    const int lane = threadIdx.x & 63;
    const int w = gid & 1;          // 0 = q, 1 = k
    const int h = (gid >> 1) & 15;
    const int n = gid >> 5;         // 0..4095
    float* p = qkv + (size_t)n * QKV_N + w * D_MODEL + h * HD + lane;
    float v = *p;
    float ss = v * v;
#pragma unroll
    for (int off = 32; off; off >>= 1) ss += __shfl_xor(ss, off);
    float nrm = sqrtf(ss);
    float scale = 1.0f / fmaxf(nrm, 1e-12f);
    *p = v * scale;
}

// ---------------- Causal YAT attention ----------------
// Block: 256 threads. Grid: (T/BQ, B*H). Q tile = 32 rows, key tile = 64.
#define BQ 32
#define BS 64

__global__ __launch_bounds__(256) void attn_kernel(const float* __restrict__ qkv,
                                                   float* __restrict__ attn_out) {
    __shared__ float Qs[BQ][HD + 1];   // 32x65
    __shared__ float Ks[BS][HD + 1];   // 64x65
    __shared__ float Vs[BS][HD];       // 64x64
    __shared__ float Ss[BQ][BS + 1];   // 32x65

    const int bh = blockIdx.y;
    const int b = bh >> 4;
    const int h = bh & 15;
    const int t0 = blockIdx.x * BQ;
    const int tid = threadIdx.x;

    const float* qbase = qkv + (size_t)b * T_SEQ * QKV_N + h * HD;
    const float* kbase = qbase + D_MODEL;
    const float* vbase = qbase + 2 * D_MODEL;

    // load Q tile: 32 rows x 64 cols; thread -> row tid>>3, 8 floats
    {
        const int r = tid >> 3;
        const int c = (tid & 7) * 8;
        const float* src = qbase + (size_t)(t0 + r) * QKV_N + c;
        float4 v0 = *(const float4*)(src);
        float4 v1 = *(const float4*)(src + 4);
        Qs[r][c + 0] = v0.x; Qs[r][c + 1] = v0.y; Qs[r][c + 2] = v0.z; Qs[r][c + 3] = v0.w;
        Qs[r][c + 4] = v1.x; Qs[r][c + 5] = v1.y; Qs[r][c + 6] = v1.z; Qs[r][c + 7] = v1.w;
    }

    const int tx = tid & 15;   // -> 4 s (score) or 4 d (PV)
    const int ty = tid >> 4;   // -> 2 t rows
    float accn[2][4] = {};
    float accd[2] = {};

    const int smax = t0 + BQ - 1;
    const int nst = (smax / BS) + 1;

    for (int st = 0; st < nst; ++st) {
        const int s0 = st * BS;
        // load K,V tiles (64x64 each): thread -> row tid>>2, 16 floats
        {
            const int r = tid >> 2;
            const int c = (tid & 3) * 16;
            const float* ksrc = kbase + (size_t)(s0 + r) * QKV_N + c;
            const float* vsrc = vbase + (size_t)(s0 + r) * QKV_N + c;
#pragma unroll
            for (int q4 = 0; q4 < 4; ++q4) {
                float4 kv = *(const float4*)(ksrc + q4 * 4);
                float4 vv = *(const float4*)(vsrc + q4 * 4);
                Ks[r][c + q4 * 4 + 0] = kv.x; Ks[r][c + q4 * 4 + 1] = kv.y;
                Ks[r][c + q4 * 4 + 2] = kv.z; Ks[r][c + q4 * 4 + 3] = kv.w;
                Vs[r][c + q4 * 4 + 0] = vv.x; Vs[r][c + q4 * 4 + 1] = vv.y;
                Vs[r][c + q4 * 4 + 2] = vv.z; Vs[r][c + q4 * 4 + 3] = vv.w;
            }
        }
        __syncthreads();

        // score phase: thread computes 2t x 4s dots over d=64
        float sc[2][4] = {};
#pragma unroll 8
        for (int d = 0; d < HD; ++d) {
            float q0 = Qs[ty * 2 + 0][d];
            float q1 = Qs[ty * 2 + 1][d];
#pragma unroll
            for (int j = 0; j < 4; ++j) {
                float kv = Ks[tx * 4 + j][d];
                sc[0][j] = fmaf(q0, kv, sc[0][j]);
                sc[1][j] = fmaf(q1, kv, sc[1][j]);
            }
        }
#pragma unroll
        for (int i = 0; i < 2; ++i) {
            const int t = t0 + ty * 2 + i;
#pragma unroll
            for (int j = 0; j < 4; ++j) {
                const int s = s0 + tx * 4 + j;
                float xd = sc[i][j];
                float den = fmaxf(2.01f - 2.0f * xd, 1e-6f);
                float Kv = (s <= t) ? (xd * xd / den) : 0.0f;
                Ss[ty * 2 + i][tx * 4 + j] = Kv;
            }
        }
        __syncthreads();

        // PV phase: thread accumulates 2t x 4d over s=64
#pragma unroll 8
        for (int s = 0; s < BS; ++s) {
            float vs[4];
#pragma unroll
            for (int j = 0; j < 4; ++j) vs[j] = Vs[s][tx * 4 + j];
#pragma unroll
            for (int i = 0; i < 2; ++i) {
                float kv = Ss[ty * 2 + i][s];
                accd[i] += kv;
#pragma unroll
                for (int j = 0; j < 4; ++j)
                    accn[i][j] = fmaf(kv, vs[j], accn[i][j]);
            }
        }
        __syncthreads();
    }

    // write attn_out[b, t, h*64 + d]
#pragma unroll
    for (int i = 0; i < 2; ++i) {
        const int t = t0 + ty * 2 + i;
        float inv = 1.0f / (accd[i] + 1e-6f);
        float4 o;
        o.x = accn[i][0] * inv; o.y = accn[i][1] * inv;
        o.z = accn[i][2] * inv; o.w = accn[i][3] * inv;
        *(float4*)(attn_out + ((size_t)b * T_SEQ + t) * D_MODEL + h * HD + tx * 4) = o;
    }
}

extern "C" void kernel_launch(void* const* d_in, const int* in_sizes, int n_in,
                              void* d_out, int out_size, void* d_ws, size_t ws_size,
                              hipStream_t stream) {
    const float* x    = (const float*)d_in[0];   // [2,2048,1024]
    const float* Wqkv = (const float*)d_in[1];   // [3072,1024]
    const float* Wout = (const float*)d_in[2];   // [1024,1024]
    float* out = (float*)d_out;                  // [2,2048,1024]

    float* qkv  = (float*)d_ws;                       // 4096 x 3072 fp32 (48 MB)
    float* attn = qkv + (size_t)BT * QKV_N;           // 4096 x 1024 fp32 (16 MB)

    // 1) qkv = x @ Wqkv.T
    gemm_abt<<<dim3(QKV_N / GBN, BT / GBM), 256, 0, stream>>>(x, Wqkv, qkv, BT, QKV_N, D_MODEL);
    // 2) normalize q, k per head row
    l2norm_qk<<<(BT * N_HEADS * 2) / 4, 256, 0, stream>>>(qkv);
    // 3) causal YAT attention
    attn_kernel<<<dim3(T_SEQ / BQ, 2 * N_HEADS), 256, 0, stream>>>(qkv, attn);
    // 4) out = attn @ Wout.T
    gemm_abt<<<dim3(D_MODEL / GBN, BT / GBM), 256, 0, stream>>>(attn, Wout, out, BT, D_MODEL, D_MODEL);
}

// Round 2
// 390.792 us; speedup vs baseline: 3.8916x; 3.8916x over previous
//
#include <hip/hip_runtime.h>
#include <hip/hip_bf16.h>

// B=2, T=2048, D=1024, H=16, hd=64
#define T_SEQ 2048
#define D_MODEL 1024
#define BT 4096
#define QKV_N 3072

typedef __attribute__((ext_vector_type(8))) short bf16x8;
typedef __attribute__((ext_vector_type(4))) short bf16x4;
typedef __attribute__((ext_vector_type(4))) float f32x4;

typedef unsigned int __attribute__((address_space(1))) as1_uint;
typedef unsigned int __attribute__((address_space(3))) as3_uint;

__device__ __forceinline__ unsigned short f2bf(float f) {
    unsigned u = __builtin_bit_cast(unsigned, f);
    u += 0x7fffu + ((u >> 16) & 1u);   // round-to-nearest-even
    return (unsigned short)(u >> 16);
}
__device__ __forceinline__ float bf2f(unsigned short h) {
    unsigned u = ((unsigned)h) << 16;
    return __builtin_bit_cast(float, u);
}
__device__ __forceinline__ void gload_lds16(const void* g, void* l) {
    __builtin_amdgcn_global_load_lds((const as1_uint*)g, (as3_uint*)l, 16, 0, 0);
}

// ---------------- fp32 -> bf16 convert (vectorized) ----------------
__global__ __launch_bounds__(256) void cvt_bf16(const float* __restrict__ src,
                                                unsigned short* __restrict__ dst, int n8) {
    const int i = blockIdx.x * 256 + threadIdx.x;
    if (i >= n8) return;
    const float4* s = (const float4*)src + (size_t)i * 2;
    const float4 a = s[0], b = s[1];
    uint4 o;
    o.x = (unsigned)f2bf(a.x) | ((unsigned)f2bf(a.y) << 16);
    o.y = (unsigned)f2bf(a.z) | ((unsigned)f2bf(a.w) << 16);
    o.z = (unsigned)f2bf(b.x) | ((unsigned)f2bf(b.y) << 16);
    o.w = (unsigned)f2bf(b.z) | ((unsigned)f2bf(b.w) << 16);
    ((uint4*)dst)[i] = o;
}

// ---------------- MFMA GEMM: C[M,N] = A[M,K] @ B[N,K]^T (bf16 in, fp32 acc) ----
// 128x128 tile, BK=32, 4 waves (2x2 of 64x64), global_load_lds staging with
// XOR k-slot swizzle: LDS slot sl holds global slot sl ^ ((row>>1)&3).
template<int OUT_BF16>
__global__ __launch_bounds__(256) void gemm_bt_mfma(const unsigned short* __restrict__ A,
                                                    const unsigned short* __restrict__ B,
                                                    void* __restrict__ Cout,
                                                    int M, int N, int K) {
    __shared__ unsigned short As[128 * 32];
    __shared__ unsigned short Bs[128 * 32];
    const int tid = threadIdx.x;
    const int w = tid >> 6;
    const int l = tid & 63;
    const int l15 = l & 15, l4 = l >> 4;
    const int bm = blockIdx.y * 128, bn = blockIdx.x * 128;
    const int wm = (w >> 1) * 64, wn = (w & 1) * 64;

    const f32x4 z = {0.f, 0.f, 0.f, 0.f};
    f32x4 acc[4][4];
#pragma unroll
    for (int m = 0; m < 4; ++m)
#pragma unroll
        for (int n = 0; n < 4; ++n) acc[m][n] = z;

    const int srow = tid >> 2;   // 0..63 row within 64-row chunk
    const int ssl = tid & 3;     // linear LDS dest k-slot (16B units)

    for (int k0 = 0; k0 < K; k0 += 32) {
#pragma unroll
        for (int c = 0; c < 2; ++c) {
            const int row = c * 64 + srow;
            const int sa = ssl ^ ((row >> 1) & 3);  // pre-swizzled global source slot
            gload_lds16(A + (size_t)(bm + row) * K + k0 + sa * 8, As + c * 2048 + w * 512);
            gload_lds16(B + (size_t)(bn + row) * K + k0 + sa * 8, Bs + c * 2048 + w * 512);
        }
        __syncthreads();
        bf16x8 af[4], bfr[4];
#pragma unroll
        for (int m = 0; m < 4; ++m) {
            const int row = wm + m * 16 + l15;
            const int sl = l4 ^ ((row >> 1) & 3);
            af[m] = *(const bf16x8*)(As + row * 32 + sl * 8);
        }
#pragma unroll
        for (int n = 0; n < 4; ++n) {
            const int row = wn + n * 16 + l15;
            const int sl = l4 ^ ((row >> 1) & 3);
            bfr[n] = *(const bf16x8*)(Bs + row * 32 + sl * 8);
        }
#pragma unroll
        for (int m = 0; m < 4; ++m)
#pragma unroll
            for (int n = 0; n < 4; ++n)
                acc[m][n] = __builtin_amdgcn_mfma_f32_16x16x32_bf16(af[m], bfr[n], acc[m][n], 0, 0, 0);
        __syncthreads();
    }
    // C layout: col = lane&15, row = (lane>>4)*4 + reg
#pragma unroll
    for (int m = 0; m < 4; ++m)
#pragma unroll
        for (int n = 0; n < 4; ++n)
#pragma unroll
            for (int r = 0; r < 4; ++r) {
                const int row = bm + wm + m * 16 + l4 * 4 + r;
                const int col = bn + wn + n * 16 + l15;
                if (OUT_BF16)
                    ((unsigned short*)Cout)[(size_t)row * N + col] = f2bf(acc[m][n][r]);
                else
                    ((float*)Cout)[(size_t)row * N + col] = acc[m][n][r];
            }
}

// ---------------- L2 normalize q,k rows -> bf16 [b][h][t][64] ----------------
__global__ __launch_bounds__(256) void l2norm_qk_cvt(const unsigned short* __restrict__ qkvb,
                                                     unsigned short* __restrict__ qb,
                                                     unsigned short* __restrict__ kb) {
    const int wid = blockIdx.x * 4 + (threadIdx.x >> 6);
    const int lane = threadIdx.x & 63;
    const int sel = wid & 1;          // 0=q 1=k
    const int h = (wid >> 1) & 15;
    const int n = wid >> 5;           // 0..4095 (b*T + t)
    const float v = bf2f(qkvb[(size_t)n * QKV_N + sel * D_MODEL + h * 64 + lane]);
    float ss = v * v;
#pragma unroll
    for (int off = 32; off; off >>= 1) ss += __shfl_xor(ss, off);
    const float sc = 1.0f / fmaxf(sqrtf(ss), 1e-12f);
    const int b = n >> 11, t = n & 2047;
    unsigned short* dst = (sel ? kb : qb) + (((size_t)(b * 16 + h) * T_SEQ + t) * 64) + lane;
    *dst = f2bf(v * sc);
}

// ---------------- V relayout: qkvb v-part -> vbT [b][h][d=64][t] bf16 ----------
__global__ __launch_bounds__(256) void v_cvt_T(const unsigned short* __restrict__ qkvb,
                                               unsigned short* __restrict__ vbT) {
    __shared__ unsigned short tile[64][72];  // [d][t], pad 8 to break conflicts
    const int bh = blockIdx.y;
    const int b = bh >> 4, h = bh & 15;
    const int t0 = blockIdx.x * 64;
    const int r = threadIdx.x >> 2;          // t within tile
    const int c = (threadIdx.x & 3) * 16;    // d chunk
    const unsigned short* src = qkvb + (size_t)(b * T_SEQ + t0 + r) * QKV_N + 2 * D_MODEL + h * 64 + c;
    uint4 v0 = *(const uint4*)(src);
    uint4 v1 = *(const uint4*)(src + 8);
    unsigned short tmp[16];
    *(uint4*)tmp = v0;
    *(uint4*)(tmp + 8) = v1;
#pragma unroll
    for (int j = 0; j < 16; ++j) tile[c + j][r] = tmp[j];
    __syncthreads();
    const int d = threadIdx.x >> 2;
    const int tc = (threadIdx.x & 3) * 16;
    unsigned short tmp2[16];
#pragma unroll
    for (int j = 0; j < 16; ++j) tmp2[j] = tile[d][tc + j];
    unsigned short* dst = vbT + ((size_t)bh * 64 + d) * T_SEQ + t0 + tc;
    *(uint4*)dst = *(uint4*)tmp2;
    *(uint4*)(dst + 8) = *(uint4*)(tmp2 + 8);
}

// ---------------- Causal YAT attention, MFMA ----------------
// Block = 4 waves; q-tile 64 rows (wave w owns rows w*16..+16). Key tiles of 64.
// QK^T and PV are mfma_f32_16x16x32_bf16; S goes through a wave-private padded
// LDS tile (no barriers anywhere).
__global__ __launch_bounds__(256) void attn_mfma(const unsigned short* __restrict__ qb,
                                                 const unsigned short* __restrict__ kb,
                                                 const unsigned short* __restrict__ vbT,
                                                 unsigned short* __restrict__ attnb) {
    __shared__ unsigned short Ss[4][16][72];   // [wave][q-row][s], pad 72 (2-way free b64 reads)
    const int tid = threadIdx.x;
    const int w = tid >> 6;
    const int l = tid & 63;
    const int l15 = l & 15, l4 = l >> 4;
    const int bh = blockIdx.y;                 // b*16 + h
    const int t0 = blockIdx.x * 64;
    const size_t hb = (size_t)bh * T_SEQ * 64;

    // Q A-fragments (rows t0 + w*16 + l15; k-elems l4*8.. ; two K=32 blocks)
    bf16x8 qf0, qf1;
    {
        const unsigned short* qp = qb + hb + (size_t)(t0 + w * 16 + l15) * 64 + l4 * 8;
        qf0 = *(const bf16x8*)(qp);
        qf1 = *(const bf16x8*)(qp + 32);
    }

    const f32x4 z = {0.f, 0.f, 0.f, 0.f};
    f32x4 acc[4];
#pragma unroll
    for (int i = 0; i < 4; ++i) acc[i] = z;
    float accd[4] = {0.f, 0.f, 0.f, 0.f};

    const int nst = blockIdx.x + 1;
    for (int st = 0; st < nst; ++st) {
        const int s0 = st * 64;
        // ---- QK^T: 4 s-fragments of 16 cols ----
        f32x4 sC[4];
#pragma unroll
        for (int sf = 0; sf < 4; ++sf) {
            const unsigned short* kp = kb + hb + (size_t)(s0 + sf * 16 + l15) * 64 + l4 * 8;
            bf16x8 kf0 = *(const bf16x8*)(kp);
            bf16x8 kf1 = *(const bf16x8*)(kp + 32);
            f32x4 c = z;
            c = __builtin_amdgcn_mfma_f32_16x16x32_bf16(qf0, kf0, c, 0, 0, 0);
            c = __builtin_amdgcn_mfma_f32_16x16x32_bf16(qf1, kf1, c, 0, 0, 0);
            sC[sf] = c;
        }
        // ---- YAT transform + causal mask + row-sum + S->bf16 into LDS ----
#pragma unroll
        for (int r = 0; r < 4; ++r) {
            const int t = t0 + w * 16 + l4 * 4 + r;
            float rowsum = 0.f;
#pragma unroll
            for (int sf = 0; sf < 4; ++sf) {
                const int s = s0 + sf * 16 + l15;
                const float xd = sC[sf][r];
                const float den = fmaxf(2.01f - 2.0f * xd, 1e-6f);
                float Kv = xd * xd * __builtin_amdgcn_rcpf(den);
                if (s > t) Kv = 0.f;
                rowsum += Kv;
                Ss[w][l4 * 4 + r][sf * 16 + l15] = f2bf(Kv);
            }
            rowsum += __shfl_xor(rowsum, 1);
            rowsum += __shfl_xor(rowsum, 2);
            rowsum += __shfl_xor(rowsum, 4);
            rowsum += __shfl_xor(rowsum, 8);
            accd[r] += rowsum;
        }
        // ---- PV: A = S (row l15), B = V^T fragments ----
#pragma unroll
        for (int df = 0; df < 4; ++df) {
            const unsigned short* vp = vbT + (size_t)bh * 64 * T_SEQ + (size_t)(df * 16 + l15) * T_SEQ + s0 + l4 * 8;
            bf16x8 vf0 = *(const bf16x8*)(vp);
            bf16x8 vf1 = *(const bf16x8*)(vp + 32);
            bf16x4 a0lo = *(const bf16x4*)(&Ss[w][l15][l4 * 8]);
            bf16x4 a0hi = *(const bf16x4*)(&Ss[w][l15][l4 * 8 + 4]);
            bf16x4 a1lo = *(const bf16x4*)(&Ss[w][l15][32 + l4 * 8]);
            bf16x4 a1hi = *(const bf16x4*)(&Ss[w][l15][32 + l4 * 8 + 4]);
            bf16x8 a0, a1;
#pragma unroll
            for (int j = 0; j < 4; ++j) {
                a0[j] = a0lo[j]; a0[j + 4] = a0hi[j];
                a1[j] = a1lo[j]; a1[j + 4] = a1hi[j];
            }
            f32x4 c = acc[df];
            c = __builtin_amdgcn_mfma_f32_16x16x32_bf16(a0, vf0, c, 0, 0, 0);
            c = __builtin_amdgcn_mfma_f32_16x16x32_bf16(a1, vf1, c, 0, 0, 0);
            acc[df] = c;
        }
    }

    const int b = bh >> 4, h = bh & 15;
#pragma unroll
    for (int df = 0; df < 4; ++df)
#pragma unroll
        for (int r = 0; r < 4; ++r) {
            const int t = t0 + w * 16 + l4 * 4 + r;
            const float o = acc[df][r] / (accd[r] + 1e-6f);
            attnb[((size_t)b * T_SEQ + t) * D_MODEL + h * 64 + df * 16 + l15] = f2bf(o);
        }
}

extern "C" void kernel_launch(void* const* d_in, const int* in_sizes, int n_in,
                              void* d_out, int out_size, void* d_ws, size_t ws_size,
                              hipStream_t stream) {
    const float* x    = (const float*)d_in[0];   // [2,2048,1024]
    const float* Wqkv = (const float*)d_in[1];   // [3072,1024]
    const float* Wout = (const float*)d_in[2];   // [1024,1024]
    float* out = (float*)d_out;                  // [2,2048,1024] fp32

    // Workspace overlay (50 MB total):
    //  [0,8M):   xb  -> later qb
    //  [8,16M):  wqkvb (6M used) -> later kb
    //  [16,40M): qkvb (24M) -> later attnb (first 8M)
    //  [40,48M): vbT
    //  [48,50M): woutb
    char* ws = (char*)d_ws;
    unsigned short* xb    = (unsigned short*)(ws);
    unsigned short* wqkvb = (unsigned short*)(ws + (size_t)8 * 1024 * 1024);
    unsigned short* qkvb  = (unsigned short*)(ws + (size_t)16 * 1024 * 1024);
    unsigned short* vbT   = (unsigned short*)(ws + (size_t)40 * 1024 * 1024);
    unsigned short* woutb = (unsigned short*)(ws + (size_t)48 * 1024 * 1024);
    unsigned short* qbp   = xb;     // [2][16][2048][64]
    unsigned short* kbp   = wqkvb;  // [2][16][2048][64]
    unsigned short* attnb = qkvb;   // [4096][1024]

    cvt_bf16<<<2048, 256, 0, stream>>>(x, xb, BT * D_MODEL / 8);
    cvt_bf16<<<1536, 256, 0, stream>>>(Wqkv, wqkvb, QKV_N * D_MODEL / 8);
    cvt_bf16<<<512, 256, 0, stream>>>(Wout, woutb, D_MODEL * D_MODEL / 8);

    gemm_bt_mfma<1><<<dim3(QKV_N / 128, BT / 128), 256, 0, stream>>>(xb, wqkvb, qkvb, BT, QKV_N, D_MODEL);

    l2norm_qk_cvt<<<BT * 32 / 4, 256, 0, stream>>>(qkvb, qbp, kbp);
    v_cvt_T<<<dim3(T_SEQ / 64, 32), 256, 0, stream>>>(qkvb, vbT);

    attn_mfma<<<dim3(T_SEQ / 64, 32), 256, 0, stream>>>(qbp, kbp, vbT, attnb);

    gemm_bt_mfma<0><<<dim3(D_MODEL / 128, BT / 128), 256, 0, stream>>>(attnb, woutb, out, BT, D_MODEL, D_MODEL);
}

// Round 3
// 227.898 us; speedup vs baseline: 6.6732x; 1.7148x over previous
//
#include <hip/hip_runtime.h>
#include <hip/hip_bf16.h>

// B=2, T=2048, D=1024, H=16, hd=64
#define T_SEQ 2048
#define D_MODEL 1024
#define BT 4096
#define QKV_N 3072

typedef __attribute__((ext_vector_type(8))) short bf16x8;
typedef __attribute__((ext_vector_type(4))) short bf16x4;
typedef __attribute__((ext_vector_type(4))) float f32x4;

typedef unsigned int __attribute__((address_space(1))) as1_uint;
typedef unsigned int __attribute__((address_space(3))) as3_uint;

__device__ __forceinline__ unsigned short f2bf(float f) {
    unsigned u = __builtin_bit_cast(unsigned, f);
    u += 0x7fffu + ((u >> 16) & 1u);   // round-to-nearest-even
    return (unsigned short)(u >> 16);
}
__device__ __forceinline__ float bf2f(unsigned short h) {
    unsigned u = ((unsigned)h) << 16;
    return __builtin_bit_cast(float, u);
}
__device__ __forceinline__ void gload_lds16(const void* g, void* l) {
    __builtin_amdgcn_global_load_lds((const as1_uint*)g, (as3_uint*)l, 16, 0, 0);
}

// ---------------- fp32 -> bf16 convert (vectorized) ----------------
__global__ __launch_bounds__(256) void cvt_bf16(const float* __restrict__ src,
                                                unsigned short* __restrict__ dst, int n8) {
    const int i = blockIdx.x * 256 + threadIdx.x;
    if (i >= n8) return;
    const float4* s = (const float4*)src + (size_t)i * 2;
    const float4 a = s[0], b = s[1];
    uint4 o;
    o.x = (unsigned)f2bf(a.x) | ((unsigned)f2bf(a.y) << 16);
    o.y = (unsigned)f2bf(a.z) | ((unsigned)f2bf(a.w) << 16);
    o.z = (unsigned)f2bf(b.x) | ((unsigned)f2bf(b.y) << 16);
    o.w = (unsigned)f2bf(b.z) | ((unsigned)f2bf(b.w) << 16);
    ((uint4*)dst)[i] = o;
}

// ---------------- MFMA GEMM: C[M,N] = A[M,K] @ B[N,K]^T (bf16 in, fp32 acc) ----
template<int OUT_BF16>
__global__ __launch_bounds__(256) void gemm_bt_mfma(const unsigned short* __restrict__ A,
                                                    const unsigned short* __restrict__ B,
                                                    void* __restrict__ Cout,
                                                    int M, int N, int K) {
    __shared__ unsigned short As[128 * 32];
    __shared__ unsigned short Bs[128 * 32];
    const int tid = threadIdx.x;
    const int w = tid >> 6;
    const int l = tid & 63;
    const int l15 = l & 15, l4 = l >> 4;
    const int bm = blockIdx.y * 128, bn = blockIdx.x * 128;
    const int wm = (w >> 1) * 64, wn = (w & 1) * 64;

    const f32x4 z = {0.f, 0.f, 0.f, 0.f};
    f32x4 acc[4][4];
#pragma unroll
    for (int m = 0; m < 4; ++m)
#pragma unroll
        for (int n = 0; n < 4; ++n) acc[m][n] = z;

    const int srow = tid >> 2;   // 0..63 row within 64-row chunk
    const int ssl = tid & 3;     // linear LDS dest k-slot (16B units)

    for (int k0 = 0; k0 < K; k0 += 32) {
#pragma unroll
        for (int c = 0; c < 2; ++c) {
            const int row = c * 64 + srow;
            const int sa = ssl ^ ((row >> 1) & 3);  // pre-swizzled global source slot
            gload_lds16(A + (size_t)(bm + row) * K + k0 + sa * 8, As + c * 2048 + w * 512);
            gload_lds16(B + (size_t)(bn + row) * K + k0 + sa * 8, Bs + c * 2048 + w * 512);
        }
        __syncthreads();
        bf16x8 af[4], bfr[4];
#pragma unroll
        for (int m = 0; m < 4; ++m) {
            const int row = wm + m * 16 + l15;
            const int sl = l4 ^ ((row >> 1) & 3);
            af[m] = *(const bf16x8*)(As + row * 32 + sl * 8);
        }
#pragma unroll
        for (int n = 0; n < 4; ++n) {
            const int row = wn + n * 16 + l15;
            const int sl = l4 ^ ((row >> 1) & 3);
            bfr[n] = *(const bf16x8*)(Bs + row * 32 + sl * 8);
        }
#pragma unroll
        for (int m = 0; m < 4; ++m)
#pragma unroll
            for (int n = 0; n < 4; ++n)
                acc[m][n] = __builtin_amdgcn_mfma_f32_16x16x32_bf16(af[m], bfr[n], acc[m][n], 0, 0, 0);
        __syncthreads();
    }
#pragma unroll
    for (int m = 0; m < 4; ++m)
#pragma unroll
        for (int n = 0; n < 4; ++n)
#pragma unroll
            for (int r = 0; r < 4; ++r) {
                const int row = bm + wm + m * 16 + l4 * 4 + r;
                const int col = bn + wn + n * 16 + l15;
                if (OUT_BF16)
                    ((unsigned short*)Cout)[(size_t)row * N + col] = f2bf(acc[m][n][r]);
                else
                    ((float*)Cout)[(size_t)row * N + col] = acc[m][n][r];
            }
}

// ---------------- L2 normalize q,k rows -> bf16 [b][h][t][64] ----------------
__global__ __launch_bounds__(256) void l2norm_qk_cvt(const unsigned short* __restrict__ qkvb,
                                                     unsigned short* __restrict__ qb,
                                                     unsigned short* __restrict__ kb) {
    const int wid = blockIdx.x * 4 + (threadIdx.x >> 6);
    const int lane = threadIdx.x & 63;
    const int sel = wid & 1;          // 0=q 1=k
    const int h = (wid >> 1) & 15;
    const int n = wid >> 5;           // 0..4095 (b*T + t)
    const float v = bf2f(qkvb[(size_t)n * QKV_N + sel * D_MODEL + h * 64 + lane]);
    float ss = v * v;
#pragma unroll
    for (int off = 32; off; off >>= 1) ss += __shfl_xor(ss, off);
    const float sc = 1.0f / fmaxf(sqrtf(ss), 1e-12f);
    const int b = n >> 11, t = n & 2047;
    unsigned short* dst = (sel ? kb : qb) + (((size_t)(b * 16 + h) * T_SEQ + t) * 64) + lane;
    *dst = f2bf(v * sc);
}

// ---------------- V relayout: qkvb v-part -> vbT [b][h][d=64][t] bf16 ----------
__global__ __launch_bounds__(256) void v_cvt_T(const unsigned short* __restrict__ qkvb,
                                               unsigned short* __restrict__ vbT) {
    __shared__ unsigned short tile[64][72];  // [d][t]
    const int bh = blockIdx.y;
    const int b = bh >> 4, h = bh & 15;
    const int t0 = blockIdx.x * 64;
    const int r = threadIdx.x >> 2;          // t within tile
    const int c = (threadIdx.x & 3) * 16;    // d chunk
    const unsigned short* src = qkvb + (size_t)(b * T_SEQ + t0 + r) * QKV_N + 2 * D_MODEL + h * 64 + c;
    uint4 v0 = *(const uint4*)(src);
    uint4 v1 = *(const uint4*)(src + 8);
    unsigned short tmp[16];
    *(uint4*)tmp = v0;
    *(uint4*)(tmp + 8) = v1;
#pragma unroll
    for (int j = 0; j < 16; ++j) tile[c + j][r] = tmp[j];
    __syncthreads();
    const int d = threadIdx.x >> 2;
    const int tc = (threadIdx.x & 3) * 16;
    unsigned short tmp2[16];
#pragma unroll
    for (int j = 0; j < 16; ++j) tmp2[j] = tile[d][tc + j];
    unsigned short* dst = vbT + ((size_t)bh * 64 + d) * T_SEQ + t0 + tc;
    *(uint4*)dst = *(uint4*)tmp2;
    *(uint4*)(dst + 8) = *(uint4*)(tmp2 + 8);
}

// ---------------- Causal YAT attention, MFMA, pipelined ----------------
// 8 waves/block, q-tile 128 (wave owns 16 rows), key tiles of 64.
// K and V^T staged in LDS (XOR-swizzled slots) via global_load_lds,
// double-buffered with counted vmcnt + raw s_barrier.
#define AT_TQ 128
#define AT_TS 64

__global__ __launch_bounds__(512) void attn_mfma(const unsigned short* __restrict__ qb,
                                                 const unsigned short* __restrict__ kb,
                                                 const unsigned short* __restrict__ vbT,
                                                 unsigned short* __restrict__ attnb) {
    __shared__ unsigned short Ks[2][64 * 64];   // [buf][row s][8 slots of 8 bf16], slot-swizzled
    __shared__ unsigned short Vs[2][64 * 64];   // [buf][row d][8 slots], slot-swizzled
    __shared__ unsigned short Ss[8][16][76];    // per-wave S tile, pad 76

    const int tid = threadIdx.x;
    const int w = tid >> 6;
    const int l = tid & 63;
    const int l15 = l & 15, l4 = l >> 4;

    // longest-first XCD-chunked decode: 4 heads per XCD, t0 descending
    const int id = blockIdx.x;              // 0..511
    const int xcd = id & 7;
    const int within = id >> 3;             // 0..63
    const int bh = xcd * 4 + (within & 3);  // 4 heads per XCD
    const int t0i = 15 - (within >> 2);     // longest blocks dispatched first
    const int t0 = t0i * AT_TQ;

    const size_t hb = (size_t)bh * T_SEQ * 64;
    const unsigned short* kb_h = kb + hb;
    const unsigned short* vb_h = vbT + hb;   // [d][t] layout, same stride

    // staging geometry: wave w stages rows w*8..w*8+7 of each 64x64 tile
    const int srow = w * 8 + (l >> 3);
    const int ssl = (l & 7) ^ (srow & 7);    // pre-swizzled global slot

    // Q A-fragments: rows t0 + w*16 + l15, d-slices l4*8 and 32+l4*8
    bf16x8 qf0, qf1;
    {
        const unsigned short* qp = qb + hb + (size_t)(t0 + w * 16 + l15) * 64 + l4 * 8;
        qf0 = *(const bf16x8*)(qp);
        qf1 = *(const bf16x8*)(qp + 32);
    }

    const f32x4 z = {0.f, 0.f, 0.f, 0.f};
    f32x4 acc[4];
#pragma unroll
    for (int i = 0; i < 4; ++i) acc[i] = z;
    float accd[4] = {0.f, 0.f, 0.f, 0.f};

    const int wrow0 = t0 + w * 16;
    const int nst = (t0 + AT_TQ) / AT_TS;    // 2*t0i + 2, block-uniform

    // prologue: stage tile 0 into buf 0 (2 loads per wave)
    gload_lds16(kb_h + (size_t)srow * 64 + ssl * 8, &Ks[0][w * 512]);
    gload_lds16(vb_h + (size_t)srow * T_SEQ + 0 + ssl * 8, &Vs[0][w * 512]);

    for (int st = 0; st < nst; ++st) {
        const int cur = st & 1;
        const int s0 = st * AT_TS;
        // issue next tile's stage before computing current
        if (st + 1 < nst) {
            const int sn = (st + 1) * AT_TS;
            gload_lds16(kb_h + (size_t)(sn + srow) * 64 + ssl * 8, &Ks[cur ^ 1][w * 512]);
            gload_lds16(vb_h + (size_t)srow * T_SEQ + sn + ssl * 8, &Vs[cur ^ 1][w * 512]);
            asm volatile("s_waitcnt vmcnt(2)" ::: "memory");
        } else {
            asm volatile("s_waitcnt vmcnt(0)" ::: "memory");
        }
        __builtin_amdgcn_sched_barrier(0);
        __builtin_amdgcn_s_barrier();   // current tile resident in LDS

        // ---- QK^T from LDS K ----
        const unsigned short* Kc = &Ks[cur][0];
        f32x4 sC[4];
#pragma unroll
        for (int sf = 0; sf < 4; ++sf) {
            const int row = sf * 16 + l15;
            const int sw = row & 7;
            bf16x8 kf0 = *(const bf16x8*)(Kc + row * 64 + ((l4 ^ sw) * 8));
            bf16x8 kf1 = *(const bf16x8*)(Kc + row * 64 + (((4 + l4) ^ sw) * 8));
            f32x4 c = z;
            c = __builtin_amdgcn_mfma_f32_16x16x32_bf16(qf0, kf0, c, 0, 0, 0);
            c = __builtin_amdgcn_mfma_f32_16x16x32_bf16(qf1, kf1, c, 0, 0, 0);
            sC[sf] = c;
        }

        // ---- YAT transform + causal mask + row-sum + S->bf16 (wave-private LDS) ----
        const bool need_mask = (s0 + AT_TS - 1 > wrow0);  // wave-uniform
#pragma unroll
        for (int r = 0; r < 4; ++r) {
            float rsum = 0.f;
#pragma unroll
            for (int sf = 0; sf < 4; ++sf) {
                const float xd = sC[sf][r];
                const float den = __builtin_fmaf(-2.0f, xd, 2.01f);  // >= 0.002 always
                float Kv = xd * xd * __builtin_amdgcn_rcpf(den);
                if (need_mask) {
                    const int s = s0 + sf * 16 + l15;
                    const int t = wrow0 + l4 * 4 + r;
                    if (s > t) Kv = 0.f;
                }
                rsum += Kv;
                Ss[w][l4 * 4 + r][sf * 16 + l15] = f2bf(Kv);
            }
            rsum += __shfl_xor(rsum, 1);
            rsum += __shfl_xor(rsum, 2);
            rsum += __shfl_xor(rsum, 4);
            rsum += __shfl_xor(rsum, 8);
            accd[r] += rsum;
        }

        // ---- PV: A = S rows (q=l15), B = V^T fragments from LDS ----
        bf16x4 p00 = *(const bf16x4*)(&Ss[w][l15][l4 * 8]);
        bf16x4 p01 = *(const bf16x4*)(&Ss[w][l15][l4 * 8 + 4]);
        bf16x4 p10 = *(const bf16x4*)(&Ss[w][l15][32 + l4 * 8]);
        bf16x4 p11 = *(const bf16x4*)(&Ss[w][l15][32 + l4 * 8 + 4]);
        bf16x8 a0, a1;
#pragma unroll
        for (int j = 0; j < 4; ++j) {
            a0[j] = p00[j]; a0[j + 4] = p01[j];
            a1[j] = p10[j]; a1[j + 4] = p11[j];
        }
        const unsigned short* Vc = &Vs[cur][0];
#pragma unroll
        for (int df = 0; df < 4; ++df) {
            const int row = df * 16 + l15;
            const int sw = row & 7;
            bf16x8 vf0 = *(const bf16x8*)(Vc + row * 64 + ((l4 ^ sw) * 8));
            bf16x8 vf1 = *(const bf16x8*)(Vc + row * 64 + (((4 + l4) ^ sw) * 8));
            f32x4 c = acc[df];
            c = __builtin_amdgcn_mfma_f32_16x16x32_bf16(a0, vf0, c, 0, 0, 0);
            c = __builtin_amdgcn_mfma_f32_16x16x32_bf16(a1, vf1, c, 0, 0, 0);
            acc[df] = c;
        }
        __builtin_amdgcn_sched_barrier(0);
        __builtin_amdgcn_s_barrier();   // all waves done with buf[cur] before overwrite
    }

    const int b = bh >> 4, h = bh & 15;
#pragma unroll
    for (int df = 0; df < 4; ++df)
#pragma unroll
        for (int r = 0; r < 4; ++r) {
            const int t = t0 + w * 16 + l4 * 4 + r;
            const float o = acc[df][r] / (accd[r] + 1e-6f);
            attnb[((size_t)b * T_SEQ + t) * D_MODEL + h * 64 + df * 16 + l15] = f2bf(o);
        }
}

extern "C" void kernel_launch(void* const* d_in, const int* in_sizes, int n_in,
                              void* d_out, int out_size, void* d_ws, size_t ws_size,
                              hipStream_t stream) {
    const float* x    = (const float*)d_in[0];   // [2,2048,1024]
    const float* Wqkv = (const float*)d_in[1];   // [3072,1024]
    const float* Wout = (const float*)d_in[2];   // [1024,1024]
    float* out = (float*)d_out;                  // [2,2048,1024] fp32

    char* ws = (char*)d_ws;
    unsigned short* xb    = (unsigned short*)(ws);
    unsigned short* wqkvb = (unsigned short*)(ws + (size_t)8 * 1024 * 1024);
    unsigned short* qkvb  = (unsigned short*)(ws + (size_t)16 * 1024 * 1024);
    unsigned short* vbT   = (unsigned short*)(ws + (size_t)40 * 1024 * 1024);
    unsigned short* woutb = (unsigned short*)(ws + (size_t)48 * 1024 * 1024);
    unsigned short* qbp   = xb;     // [2][16][2048][64]
    unsigned short* kbp   = wqkvb;  // [2][16][2048][64]
    unsigned short* attnb = qkvb;   // [4096][1024]

    cvt_bf16<<<2048, 256, 0, stream>>>(x, xb, BT * D_MODEL / 8);
    cvt_bf16<<<1536, 256, 0, stream>>>(Wqkv, wqkvb, QKV_N * D_MODEL / 8);
    cvt_bf16<<<512, 256, 0, stream>>>(Wout, woutb, D_MODEL * D_MODEL / 8);

    gemm_bt_mfma<1><<<dim3(QKV_N / 128, BT / 128), 256, 0, stream>>>(xb, wqkvb, qkvb, BT, QKV_N, D_MODEL);

    l2norm_qk_cvt<<<BT * 32 / 4, 256, 0, stream>>>(qkvb, qbp, kbp);
    v_cvt_T<<<dim3(T_SEQ / 64, 32), 256, 0, stream>>>(qkvb, vbT);

    attn_mfma<<<512, 512, 0, stream>>>(qbp, kbp, vbT, attnb);

    gemm_bt_mfma<0><<<dim3(D_MODEL / 128, BT / 128), 256, 0, stream>>>(attnb, woutb, out, BT, D_MODEL, D_MODEL);
}

// Round 5
// 205.600 us; speedup vs baseline: 7.3969x; 1.1085x over previous
//
#include <hip/hip_runtime.h>
#include <hip/hip_bf16.h>

// B=2, T=2048, D=1024, H=16, hd=64
#define T_SEQ 2048
#define D_MODEL 1024
#define BT 4096
#define QKV_N 3072

typedef __attribute__((ext_vector_type(8))) short bf16x8;
typedef __attribute__((ext_vector_type(4))) short bf16x4;
typedef __attribute__((ext_vector_type(4))) float f32x4;

typedef unsigned int __attribute__((address_space(1))) as1_uint;
typedef unsigned int __attribute__((address_space(3))) as3_uint;

__device__ __forceinline__ unsigned short f2bf(float f) {
    unsigned u = __builtin_bit_cast(unsigned, f);
    u += 0x7fffu + ((u >> 16) & 1u);   // round-to-nearest-even
    return (unsigned short)(u >> 16);
}
__device__ __forceinline__ float bf2f(unsigned short h) {
    unsigned u = ((unsigned)h) << 16;
    return __builtin_bit_cast(float, u);
}
__device__ __forceinline__ void gload_lds16(const void* g, void* l) {
    __builtin_amdgcn_global_load_lds((const as1_uint*)g, (as3_uint*)l, 16, 0, 0);
}
__device__ __forceinline__ unsigned cvtpk_bf16(float lo, float hi) {
    unsigned r;
    asm("v_cvt_pk_bf16_f32 %0, %1, %2" : "=v"(r) : "v"(lo), "v"(hi));
    return r;
}

// ---------------- fp32 -> bf16 convert, all three tensors in one launch ------
__global__ __launch_bounds__(256) void cvt_bf16_3(const float* __restrict__ s0, unsigned short* __restrict__ d0, int n0,
                                                  const float* __restrict__ s1, unsigned short* __restrict__ d1, int n1,
                                                  const float* __restrict__ s2, unsigned short* __restrict__ d2, int n2) {
    int i = blockIdx.x * 256 + threadIdx.x;   // 8-element units
    const float* s; unsigned short* d;
    if (i < n0) { s = s0; d = d0; }
    else if (i < n0 + n1) { i -= n0; s = s1; d = d1; }
    else if (i < n0 + n1 + n2) { i -= n0 + n1; s = s2; d = d2; }
    else return;
    const float4* sp = (const float4*)s + (size_t)i * 2;
    const float4 a = sp[0], b = sp[1];
    uint4 o;
    o.x = (unsigned)f2bf(a.x) | ((unsigned)f2bf(a.y) << 16);
    o.y = (unsigned)f2bf(a.z) | ((unsigned)f2bf(a.w) << 16);
    o.z = (unsigned)f2bf(b.x) | ((unsigned)f2bf(b.y) << 16);
    o.w = (unsigned)f2bf(b.z) | ((unsigned)f2bf(b.w) << 16);
    ((uint4*)d)[i] = o;
}

// ---------------- MFMA GEMM: C[M,N] = A[M,K] @ B[N,K]^T (bf16 in, fp32 acc) ----
// m97 structure: 128x128 tile, BK=64, 4 waves, global_load_lds width 16,
// slot-XOR swizzle keyed on row&7. 1D grid, XCD-chunked decode.
template<int OUT_BF16>
__global__ __launch_bounds__(256) void gemm_bt_mfma(const unsigned short* __restrict__ A,
                                                    const unsigned short* __restrict__ B,
                                                    void* __restrict__ Cout,
                                                    int M, int N, int K) {
    __shared__ unsigned short As[128 * 64];
    __shared__ unsigned short Bs[128 * 64];
    const int tid = threadIdx.x;
    const int w = tid >> 6;
    const int l = tid & 63;
    const int l15 = l & 15, l4 = l >> 4;

    // XCD-chunked: each XCD gets a contiguous run of n-strips x 32 m-tiles
    const int nblocks = (M / 128) * (N / 128);
    const int cpx = nblocks >> 3;
    const int id2 = (blockIdx.x & 7) * cpx + (blockIdx.x >> 3);
    const int bm = (id2 & 31) * 128;
    const int bn = (id2 >> 5) * 128;

    const int wm = (w >> 1) * 64, wn = (w & 1) * 64;

    const f32x4 z = {0.f, 0.f, 0.f, 0.f};
    f32x4 acc[4][4];
#pragma unroll
    for (int m = 0; m < 4; ++m)
#pragma unroll
        for (int n = 0; n < 4; ++n) acc[m][n] = z;

    const int lrow = l >> 3;
    const int lslot = (l & 7) ^ (lrow & 7);   // pre-swizzled global source slot

    for (int k0 = 0; k0 < K; k0 += 64) {
#pragma unroll
        for (int i = 0; i < 4; ++i) {
            const int row = w * 32 + i * 8 + lrow;
            gload_lds16(A + (size_t)(bm + row) * K + k0 + lslot * 8, As + (w * 4 + i) * 512);
            gload_lds16(B + (size_t)(bn + row) * K + k0 + lslot * 8, Bs + (w * 4 + i) * 512);
        }
        __syncthreads();
        bf16x8 af[4][2], bfr[4][2];
#pragma unroll
        for (int m = 0; m < 4; ++m) {
            const int row = wm + m * 16 + l15;
            af[m][0] = *(const bf16x8*)(As + row * 64 + ((l4 ^ (row & 7)) * 8));
            af[m][1] = *(const bf16x8*)(As + row * 64 + (((4 + l4) ^ (row & 7)) * 8));
        }
#pragma unroll
        for (int n = 0; n < 4; ++n) {
            const int row = wn + n * 16 + l15;
            bfr[n][0] = *(const bf16x8*)(Bs + row * 64 + ((l4 ^ (row & 7)) * 8));
            bfr[n][1] = *(const bf16x8*)(Bs + row * 64 + (((4 + l4) ^ (row & 7)) * 8));
        }
#pragma unroll
        for (int m = 0; m < 4; ++m)
#pragma unroll
            for (int n = 0; n < 4; ++n) {
                acc[m][n] = __builtin_amdgcn_mfma_f32_16x16x32_bf16(af[m][0], bfr[n][0], acc[m][n], 0, 0, 0);
                acc[m][n] = __builtin_amdgcn_mfma_f32_16x16x32_bf16(af[m][1], bfr[n][1], acc[m][n], 0, 0, 0);
            }
        __syncthreads();
    }
#pragma unroll
    for (int m = 0; m < 4; ++m)
#pragma unroll
        for (int n = 0; n < 4; ++n)
#pragma unroll
            for (int r = 0; r < 4; ++r) {
                const int row = bm + wm + m * 16 + l4 * 4 + r;
                const int col = bn + wn + n * 16 + l15;
                if (OUT_BF16)
                    ((unsigned short*)Cout)[(size_t)row * N + col] = f2bf(acc[m][n][r]);
                else
                    ((float*)Cout)[(size_t)row * N + col] = acc[m][n][r];
            }
}

// ---------------- L2 normalize q,k rows -> bf16 [b][h][t][64] ----------------
__global__ __launch_bounds__(256) void l2norm_qk_cvt(const unsigned short* __restrict__ qkvb,
                                                     unsigned short* __restrict__ qb,
                                                     unsigned short* __restrict__ kb) {
    const int wid = blockIdx.x * 4 + (threadIdx.x >> 6);
    const int lane = threadIdx.x & 63;
    const int sel = wid & 1;          // 0=q 1=k
    const int h = (wid >> 1) & 15;
    const int n = wid >> 5;           // 0..4095 (b*T + t)
    const float v = bf2f(qkvb[(size_t)n * QKV_N + sel * D_MODEL + h * 64 + lane]);
    float ss = v * v;
#pragma unroll
    for (int off = 32; off; off >>= 1) ss += __shfl_xor(ss, off);
    const float sc = 1.0f / fmaxf(sqrtf(ss), 1e-12f);
    const int b = n >> 11, t = n & 2047;
    unsigned short* dst = (sel ? kb : qb) + (((size_t)(b * 16 + h) * T_SEQ + t) * 64) + lane;
    *dst = f2bf(v * sc);
}

// ---------------- V relayout: qkvb v-part -> vbT [b][h][d=64][t] bf16 ----------
__global__ __launch_bounds__(256) void v_cvt_T(const unsigned short* __restrict__ qkvb,
                                               unsigned short* __restrict__ vbT) {
    __shared__ unsigned short tile[64][72];  // [d][t]
    const int bh = blockIdx.y;
    const int b = bh >> 4, h = bh & 15;
    const int t0 = blockIdx.x * 64;
    const int r = threadIdx.x >> 2;          // t within tile
    const int c = (threadIdx.x & 3) * 16;    // d chunk
    const unsigned short* src = qkvb + (size_t)(b * T_SEQ + t0 + r) * QKV_N + 2 * D_MODEL + h * 64 + c;
    uint4 v0 = *(const uint4*)(src);
    uint4 v1 = *(const uint4*)(src + 8);
    unsigned short tmp[16];
    *(uint4*)tmp = v0;
    *(uint4*)(tmp + 8) = v1;
#pragma unroll
    for (int j = 0; j < 16; ++j) tile[c + j][r] = tmp[j];
    __syncthreads();
    const int d = threadIdx.x >> 2;
    const int tc = (threadIdx.x & 3) * 16;
    unsigned short tmp2[16];
#pragma unroll
    for (int j = 0; j < 16; ++j) tmp2[j] = tile[d][tc + j];
    unsigned short* dst = vbT + ((size_t)bh * 64 + d) * T_SEQ + t0 + tc;
    *(uint4*)dst = *(uint4*)tmp2;
    *(uint4*)(dst + 8) = *(uint4*)(tmp2 + 8);
}

// ---------------- Causal YAT attention, MFMA, pipelined, swapped-QK ----------
// 4 waves/block, q-tile 64 (wave owns 16 rows = col dim of swapped QK^T),
// key tiles of 64, K/V^T double-buffered in LDS via global_load_lds + counted
// vmcnt. Swapped QK^T (mfma(K,Q)) makes each lane hold exactly the score
// values its PV A-slots need under slot-permutation sigma applied to BOTH
// PV operands: A slot (l4,j) <- S[q=l15][s = (j>>2)*16 + l4*4 + (j&3)],
// B slot (l4,j) <- V[s][d]. No S LDS round-trip, no cross-lane ops.
#define AT_TS 64

__global__ __launch_bounds__(256) void attn_mfma(const unsigned short* __restrict__ qb,
                                                 const unsigned short* __restrict__ kb,
                                                 const unsigned short* __restrict__ vbT,
                                                 unsigned short* __restrict__ attnb) {
    __shared__ unsigned short Ks[2][64 * 64];   // [buf][s-row][8 slots of 8], slot-swizzled
    __shared__ unsigned short Vs[2][64 * 64];   // [buf][d-row][8 slots], slot-swizzled

    const int tid = threadIdx.x;
    const int w = tid >> 6;
    const int l = tid & 63;
    const int l15 = l & 15, l4 = l >> 4;

    // XCD-chunked, longest-first: 4 heads per XCD, t0 descending
    const int id = blockIdx.x;               // 0..1023
    const int xcd = id & 7;
    const int within = id >> 3;              // 0..127
    const int bh = xcd * 4 + (within & 3);
    const int t0i = 31 - (within >> 2);      // 0..31
    const int t0 = t0i * 64;

    const size_t hb = (size_t)bh * T_SEQ * 64;
    const unsigned short* kb_h = kb + hb;
    const unsigned short* vb_h = vbT + hb;   // [d][t]

    // staging: thread stages 2 chunks of K and 2 of V per tile
    const int lrow = l >> 3;
    const int lslot = (l & 7) ^ (lrow & 7);

    // Q B-fragment: col = q = l15 (wave rows t0 + w*16 + l15), k = d
    bf16x8 qf0, qf1;
    {
        const unsigned short* qp = qb + hb + (size_t)(t0 + w * 16 + l15) * 64 + l4 * 8;
        qf0 = *(const bf16x8*)(qp);
        qf1 = *(const bf16x8*)(qp + 32);
    }

    const f32x4 z = {0.f, 0.f, 0.f, 0.f};
    f32x4 acc[4];
#pragma unroll
    for (int i = 0; i < 4; ++i) acc[i] = z;
    float accd = 0.f;                        // denominator partial for q = l15

    const int wrow0 = t0 + w * 16;
    const int tq = wrow0 + l15;              // this lane's q row
    const int nst = t0i + 1;

    // prologue: stage tile 0 into buf 0 (4 loads per thread)
#pragma unroll
    for (int c = 0; c < 2; ++c) {
        const int row = w * 16 + c * 8 + lrow;
        gload_lds16(kb_h + (size_t)row * 64 + lslot * 8, &Ks[0][(w * 2 + c) * 512]);
        gload_lds16(vb_h + (size_t)row * T_SEQ + lslot * 8, &Vs[0][(w * 2 + c) * 512]);
    }

    for (int st = 0; st < nst; ++st) {
        const int cur = st & 1;
        const int s0 = st * AT_TS;
        if (st + 1 < nst) {
            const int sn = (st + 1) * AT_TS;
#pragma unroll
            for (int c = 0; c < 2; ++c) {
                const int row = w * 16 + c * 8 + lrow;
                gload_lds16(kb_h + (size_t)(sn + row) * 64 + lslot * 8, &Ks[cur ^ 1][(w * 2 + c) * 512]);
                gload_lds16(vb_h + (size_t)row * T_SEQ + sn + lslot * 8, &Vs[cur ^ 1][(w * 2 + c) * 512]);
            }
            asm volatile("s_waitcnt vmcnt(4)" ::: "memory");
        } else {
            asm volatile("s_waitcnt vmcnt(0)" ::: "memory");
        }
        __builtin_amdgcn_sched_barrier(0);
        __builtin_amdgcn_s_barrier();   // current tile resident

        // ---- swapped QK^T: sC[sf] rows = s (sf*16 + l4*4 + r), col = q = l15 ----
        const unsigned short* Kc = &Ks[cur][0];
        f32x4 sC[4];
#pragma unroll
        for (int sf = 0; sf < 4; ++sf) {
            const int row = sf * 16 + l15;
            bf16x8 kf0 = *(const bf16x8*)(Kc + row * 64 + ((l4 ^ (row & 7)) * 8));
            bf16x8 kf1 = *(const bf16x8*)(Kc + row * 64 + (((4 + l4) ^ (row & 7)) * 8));
            f32x4 c = z;
            c = __builtin_amdgcn_mfma_f32_16x16x32_bf16(kf0, qf0, c, 0, 0, 0);
            c = __builtin_amdgcn_mfma_f32_16x16x32_bf16(kf1, qf1, c, 0, 0, 0);
            sC[sf] = c;
        }

        // ---- YAT transform + causal mask + lane-local row-sum ----
        const bool need_mask = (s0 + AT_TS - 1 > wrow0);  // wave-uniform
        float part = 0.f;
#pragma unroll
        for (int sf = 0; sf < 4; ++sf)
#pragma unroll
            for (int r = 0; r < 4; ++r) {
                const float xd = sC[sf][r];
                const float den = __builtin_fmaf(-2.0f, xd, 2.01f);
                float Kv = xd * xd * __builtin_amdgcn_rcpf(den);
                if (need_mask) {
                    const int s = s0 + sf * 16 + l4 * 4 + r;
                    if (s > tq) Kv = 0.f;
                }
                part += Kv;
                sC[sf][r] = Kv;
            }
        accd += part;

        // ---- pack A-frags: a0 = s-slots sf 0..1, a1 = sf 2..3 ----
        uint4 p0, p1;
        p0.x = cvtpk_bf16(sC[0][0], sC[0][1]);
        p0.y = cvtpk_bf16(sC[0][2], sC[0][3]);
        p0.z = cvtpk_bf16(sC[1][0], sC[1][1]);
        p0.w = cvtpk_bf16(sC[1][2], sC[1][3]);
        p1.x = cvtpk_bf16(sC[2][0], sC[2][1]);
        p1.y = cvtpk_bf16(sC[2][2], sC[2][3]);
        p1.z = cvtpk_bf16(sC[3][0], sC[3][1]);
        p1.w = cvtpk_bf16(sC[3][2], sC[3][3]);
        const bf16x8 a0 = __builtin_bit_cast(bf16x8, p0);
        const bf16x8 a1 = __builtin_bit_cast(bf16x8, p1);

        // ---- PV: B slot (l4,j) = V[s = sigma(l4,j)][d], 4x b64 per mfma-pair ----
        const unsigned short* Vc = &Vs[cur][0];
#pragma unroll
        for (int df = 0; df < 4; ++df) {
            const int row = df * 16 + l15;       // d
            const int p = row & 7;
            const int base = row * 64;
            const int off = (l4 & 1) * 4;
            bf16x4 v0 = *(const bf16x4*)(Vc + base + (((l4 >> 1) + 0) ^ p) * 8 + off);
            bf16x4 v1 = *(const bf16x4*)(Vc + base + (((l4 >> 1) + 2) ^ p) * 8 + off);
            bf16x4 v2 = *(const bf16x4*)(Vc + base + (((l4 >> 1) + 4) ^ p) * 8 + off);
            bf16x4 v3 = *(const bf16x4*)(Vc + base + (((l4 >> 1) + 6) ^ p) * 8 + off);
            bf16x8 B0, B1;
#pragma unroll
            for (int j = 0; j < 4; ++j) {
                B0[j] = v0[j]; B0[j + 4] = v1[j];
                B1[j] = v2[j]; B1[j + 4] = v3[j];
            }
            acc[df] = __builtin_amdgcn_mfma_f32_16x16x32_bf16(a0, B0, acc[df], 0, 0, 0);
            acc[df] = __builtin_amdgcn_mfma_f32_16x16x32_bf16(a1, B1, acc[df], 0, 0, 0);
        }
        __builtin_amdgcn_sched_barrier(0);
        __builtin_amdgcn_s_barrier();   // all waves done with buf[cur]
    }

    // denominator: reduce across l4 groups (disjoint s ranges), then fetch per-row
    accd += __shfl_xor(accd, 16);
    accd += __shfl_xor(accd, 32);

    const int b = bh >> 4, h = bh & 15;
#pragma unroll
    for (int r = 0; r < 4; ++r) {
        const float den = __shfl(accd, l4 * 4 + r) + 1e-6f;
#pragma unroll
        for (int df = 0; df < 4; ++df) {
            const int t = wrow0 + l4 * 4 + r;
            const float o = acc[df][r] / den;
            attnb[((size_t)b * T_SEQ + t) * D_MODEL + h * 64 + df * 16 + l15] = f2bf(o);
        }
    }
}

extern "C" void kernel_launch(void* const* d_in, const int* in_sizes, int n_in,
                              void* d_out, int out_size, void* d_ws, size_t ws_size,
                              hipStream_t stream) {
    const float* x    = (const float*)d_in[0];   // [2,2048,1024]
    const float* Wqkv = (const float*)d_in[1];   // [3072,1024]
    const float* Wout = (const float*)d_in[2];   // [1024,1024]
    float* out = (float*)d_out;                  // [2,2048,1024] fp32

    char* ws = (char*)d_ws;
    unsigned short* xb    = (unsigned short*)(ws);
    unsigned short* wqkvb = (unsigned short*)(ws + (size_t)8 * 1024 * 1024);
    unsigned short* qkvb  = (unsigned short*)(ws + (size_t)16 * 1024 * 1024);
    unsigned short* vbT   = (unsigned short*)(ws + (size_t)40 * 1024 * 1024);
    unsigned short* woutb = (unsigned short*)(ws + (size_t)48 * 1024 * 1024);
    unsigned short* qbp   = xb;     // [2][16][2048][64]
    unsigned short* kbp   = wqkvb;  // [2][16][2048][64]
    unsigned short* attnb = qkvb;   // [4096][1024]

    cvt_bf16_3<<<4096, 256, 0, stream>>>(x, xb, BT * D_MODEL / 8,
                                         Wqkv, wqkvb, QKV_N * D_MODEL / 8,
                                         Wout, woutb, D_MODEL * D_MODEL / 8);

    gemm_bt_mfma<1><<<(QKV_N / 128) * (BT / 128), 256, 0, stream>>>(xb, wqkvb, qkvb, BT, QKV_N, D_MODEL);

    l2norm_qk_cvt<<<BT * 32 / 4, 256, 0, stream>>>(qkvb, qbp, kbp);
    v_cvt_T<<<dim3(T_SEQ / 64, 32), 256, 0, stream>>>(qkvb, vbT);

    attn_mfma<<<1024, 256, 0, stream>>>(qbp, kbp, vbT, attnb);

    gemm_bt_mfma<0><<<(D_MODEL / 128) * (BT / 128), 256, 0, stream>>>(attnb, woutb, out, BT, D_MODEL, D_MODEL);
}

// Round 6
// 179.863 us; speedup vs baseline: 8.4553x; 1.1431x over previous
//
#include <hip/hip_runtime.h>
#include <hip/hip_bf16.h>

// B=2, T=2048, D=1024, H=16, hd=64
#define T_SEQ 2048
#define D_MODEL 1024
#define BT 4096
#define QKV_N 3072

typedef __attribute__((ext_vector_type(8))) short bf16x8;
typedef __attribute__((ext_vector_type(4))) short bf16x4;
typedef __attribute__((ext_vector_type(4))) float f32x4;

typedef unsigned int __attribute__((address_space(1))) as1_uint;
typedef unsigned int __attribute__((address_space(3))) as3_uint;

__device__ __forceinline__ unsigned short f2bf(float f) {
    unsigned u = __builtin_bit_cast(unsigned, f);
    u += 0x7fffu + ((u >> 16) & 1u);   // round-to-nearest-even
    return (unsigned short)(u >> 16);
}
__device__ __forceinline__ float bf2f(unsigned short h) {
    unsigned u = ((unsigned)h) << 16;
    return __builtin_bit_cast(float, u);
}
__device__ __forceinline__ void gload_lds16(const void* g, void* l) {
    __builtin_amdgcn_global_load_lds((const as1_uint*)g, (as3_uint*)l, 16, 0, 0);
}
__device__ __forceinline__ unsigned cvtpk_bf16(float lo, float hi) {
    unsigned r;
    asm("v_cvt_pk_bf16_f32 %0, %1, %2" : "=v"(r) : "v"(lo), "v"(hi));
    return r;
}

// ---------------- fp32 -> bf16 convert, all three tensors in one launch ------
__global__ __launch_bounds__(256) void cvt_bf16_3(const float* __restrict__ s0, unsigned short* __restrict__ d0, int n0,
                                                  const float* __restrict__ s1, unsigned short* __restrict__ d1, int n1,
                                                  const float* __restrict__ s2, unsigned short* __restrict__ d2, int n2) {
    int i = blockIdx.x * 256 + threadIdx.x;   // 8-element units
    const float* s; unsigned short* d;
    if (i < n0) { s = s0; d = d0; }
    else if (i < n0 + n1) { i -= n0; s = s1; d = d1; }
    else if (i < n0 + n1 + n2) { i -= n0 + n1; s = s2; d = d2; }
    else return;
    const float4* sp = (const float4*)s + (size_t)i * 2;
    const float4 a = sp[0], b = sp[1];
    uint4 o;
    o.x = (unsigned)f2bf(a.x) | ((unsigned)f2bf(a.y) << 16);
    o.y = (unsigned)f2bf(a.z) | ((unsigned)f2bf(a.w) << 16);
    o.z = (unsigned)f2bf(b.x) | ((unsigned)f2bf(b.y) << 16);
    o.w = (unsigned)f2bf(b.z) | ((unsigned)f2bf(b.w) << 16);
    ((uint4*)d)[i] = o;
}

// ---------------- MFMA GEMM: C[M,N] = A[M,K] @ B[N,K]^T (bf16 in, fp32 acc) ----
// m97 structure: 128x128 tile, BK=64, 4 waves, global_load_lds width 16,
// slot-XOR swizzle keyed on row&7. 1D grid, XCD-chunked decode.
// MODE 0: fp32 C write.  MODE 2: fused QKV epilogue — q/k waves L2-normalize
// their head (64 cols = one wave) and write bf16 to qb/kb [bh][t][64];
// v waves write bf16 to vrow [4096][1024].
template<int MODE>
__global__ __launch_bounds__(256) void gemm_bt_mfma(const unsigned short* __restrict__ A,
                                                    const unsigned short* __restrict__ B,
                                                    void* __restrict__ Cout,
                                                    unsigned short* __restrict__ qbp,
                                                    unsigned short* __restrict__ kbp,
                                                    int M, int N, int K) {
    __shared__ unsigned short As[128 * 64];
    __shared__ unsigned short Bs[128 * 64];
    const int tid = threadIdx.x;
    const int w = tid >> 6;
    const int l = tid & 63;
    const int l15 = l & 15, l4 = l >> 4;

    // XCD-chunked: each XCD gets a contiguous run of n-strips x 32 m-tiles
    const int nblocks = (M / 128) * (N / 128);
    const int cpx = nblocks >> 3;
    const int id2 = (blockIdx.x & 7) * cpx + (blockIdx.x >> 3);
    const int bm = (id2 & 31) * 128;
    const int bn = (id2 >> 5) * 128;

    const int wm = (w >> 1) * 64, wn = (w & 1) * 64;

    const f32x4 z = {0.f, 0.f, 0.f, 0.f};
    f32x4 acc[4][4];
#pragma unroll
    for (int m = 0; m < 4; ++m)
#pragma unroll
        for (int n = 0; n < 4; ++n) acc[m][n] = z;

    const int lrow = l >> 3;
    const int lslot = (l & 7) ^ (lrow & 7);   // pre-swizzled global source slot

    for (int k0 = 0; k0 < K; k0 += 64) {
#pragma unroll
        for (int i = 0; i < 4; ++i) {
            const int row = w * 32 + i * 8 + lrow;
            gload_lds16(A + (size_t)(bm + row) * K + k0 + lslot * 8, As + (w * 4 + i) * 512);
            gload_lds16(B + (size_t)(bn + row) * K + k0 + lslot * 8, Bs + (w * 4 + i) * 512);
        }
        __syncthreads();
        bf16x8 af[4][2], bfr[4][2];
#pragma unroll
        for (int m = 0; m < 4; ++m) {
            const int row = wm + m * 16 + l15;
            af[m][0] = *(const bf16x8*)(As + row * 64 + ((l4 ^ (row & 7)) * 8));
            af[m][1] = *(const bf16x8*)(As + row * 64 + (((4 + l4) ^ (row & 7)) * 8));
        }
#pragma unroll
        for (int n = 0; n < 4; ++n) {
            const int row = wn + n * 16 + l15;
            bfr[n][0] = *(const bf16x8*)(Bs + row * 64 + ((l4 ^ (row & 7)) * 8));
            bfr[n][1] = *(const bf16x8*)(Bs + row * 64 + (((4 + l4) ^ (row & 7)) * 8));
        }
#pragma unroll
        for (int m = 0; m < 4; ++m)
#pragma unroll
            for (int n = 0; n < 4; ++n) {
                acc[m][n] = __builtin_amdgcn_mfma_f32_16x16x32_bf16(af[m][0], bfr[n][0], acc[m][n], 0, 0, 0);
                acc[m][n] = __builtin_amdgcn_mfma_f32_16x16x32_bf16(af[m][1], bfr[n][1], acc[m][n], 0, 0, 0);
            }
        __syncthreads();
    }

    if (MODE == 0) {
#pragma unroll
        for (int m = 0; m < 4; ++m)
#pragma unroll
            for (int n = 0; n < 4; ++n)
#pragma unroll
                for (int r = 0; r < 4; ++r) {
                    const int row = bm + wm + m * 16 + l4 * 4 + r;
                    const int col = bn + wn + n * 16 + l15;
                    ((float*)Cout)[(size_t)row * N + col] = acc[m][n][r];
                }
    } else {
        // fused QKV epilogue. Wave's 64 cols = exactly one head of q, k or v.
        const int gcol0 = bn + wn;
        const int part = gcol0 >> 10;        // 0=q 1=k 2=v (wave-uniform)
        const int h = (gcol0 >> 6) & 15;
        if (part < 2) {
            unsigned short* dst = part ? kbp : qbp;
#pragma unroll
            for (int m = 0; m < 4; ++m)
#pragma unroll
                for (int r = 0; r < 4; ++r) {
                    float ss = 0.f;
#pragma unroll
                    for (int n = 0; n < 4; ++n) ss = fmaf(acc[m][n][r], acc[m][n][r], ss);
                    ss += __shfl_xor(ss, 1);
                    ss += __shfl_xor(ss, 2);
                    ss += __shfl_xor(ss, 4);
                    ss += __shfl_xor(ss, 8);
                    const float sc = 1.0f / fmaxf(sqrtf(ss), 1e-12f);
                    const int row = bm + wm + m * 16 + l4 * 4 + r;
                    const int bh2 = (row >> 11) * 16 + h;
                    unsigned short* pdst = dst + ((size_t)bh2 * T_SEQ + (row & 2047)) * 64 + l15;
#pragma unroll
                    for (int n = 0; n < 4; ++n) pdst[n * 16] = f2bf(acc[m][n][r] * sc);
                }
        } else {
            unsigned short* vrow = (unsigned short*)Cout;    // [4096][1024]
            const int vcol0 = gcol0 - 2048;
#pragma unroll
            for (int m = 0; m < 4; ++m)
#pragma unroll
                for (int n = 0; n < 4; ++n)
#pragma unroll
                    for (int r = 0; r < 4; ++r) {
                        const int row = bm + wm + m * 16 + l4 * 4 + r;
                        vrow[(size_t)row * D_MODEL + vcol0 + n * 16 + l15] = f2bf(acc[m][n][r]);
                    }
        }
    }
}

// ---------------- V relayout: vrow [b][t][h*64+d] -> vbT [b][h][d][t] --------
__global__ __launch_bounds__(256) void v_cvt_T(const unsigned short* __restrict__ vrow,
                                               unsigned short* __restrict__ vbT) {
    __shared__ unsigned short tile[64][72];  // [d][t]
    const int bh = blockIdx.y;
    const int b = bh >> 4, h = bh & 15;
    const int t0 = blockIdx.x * 64;
    const int r = threadIdx.x >> 2;          // t within tile
    const int c = (threadIdx.x & 3) * 16;    // d chunk
    const unsigned short* src = vrow + (size_t)(b * T_SEQ + t0 + r) * D_MODEL + h * 64 + c;
    uint4 v0 = *(const uint4*)(src);
    uint4 v1 = *(const uint4*)(src + 8);
    unsigned short tmp[16];
    *(uint4*)tmp = v0;
    *(uint4*)(tmp + 8) = v1;
#pragma unroll
    for (int j = 0; j < 16; ++j) tile[c + j][r] = tmp[j];
    __syncthreads();
    const int d = threadIdx.x >> 2;
    const int tc = (threadIdx.x & 3) * 16;
    unsigned short tmp2[16];
#pragma unroll
    for (int j = 0; j < 16; ++j) tmp2[j] = tile[d][tc + j];
    unsigned short* dst = vbT + ((size_t)bh * 64 + d) * T_SEQ + t0 + tc;
    *(uint4*)dst = *(uint4*)tmp2;
    *(uint4*)(dst + 8) = *(uint4*)(tmp2 + 8);
}

// ---------------- Causal YAT attention, MFMA, pipelined, swapped-QK ----------
// 4 waves/block, q-tile 64 (wave owns 16 rows), key tiles of 64, K/V^T
// double-buffered in LDS via global_load_lds + counted vmcnt. Swapped QK^T
// (mfma(K,Q)) + slot-permutation sigma on both PV operands: no S LDS
// round-trip, no cross-lane ops. All LDS read/staging addresses hoisted to
// registers (st-invariant bases + imm offsets + buf toggles).
#define AT_TS 64

__global__ __launch_bounds__(256) void attn_mfma(const unsigned short* __restrict__ qb,
                                                 const unsigned short* __restrict__ kb,
                                                 const unsigned short* __restrict__ vbT,
                                                 unsigned short* __restrict__ attnb) {
    __shared__ unsigned short Ks[2][64 * 64];   // [buf][s-row][8 slots of 8], slot-swizzled
    __shared__ unsigned short Vs[2][64 * 64];   // [buf][d-row][8 slots], slot-swizzled

    const int tid = threadIdx.x;
    const int w = tid >> 6;
    const int l = tid & 63;
    const int l15 = l & 15, l4 = l >> 4;

    // XCD-chunked, longest-first: 4 heads per XCD, t0 descending
    const int id = blockIdx.x;               // 0..1023
    const int xcd = id & 7;
    const int within = id >> 3;              // 0..127
    const int bh = xcd * 4 + (within & 3);
    const int t0i = 31 - (within >> 2);      // 0..31
    const int t0 = t0i * 64;

    const size_t hb = (size_t)bh * T_SEQ * 64;

    // ---- staging pointers (advanced incrementally per step) ----
    const int lrow = l >> 3;
    const int lslot = (l & 7) ^ (lrow & 7);
    const unsigned short* kgp[2];
    const unsigned short* vgp[2];
    unsigned short* kdst[2];
    unsigned short* vdst[2];
#pragma unroll
    for (int c = 0; c < 2; ++c) {
        const int row = w * 16 + c * 8 + lrow;
        kgp[c] = kb + hb + (size_t)row * 64 + lslot * 8;
        vgp[c] = vbT + hb + (size_t)row * T_SEQ + lslot * 8;
        kdst[c] = &Ks[0][(w * 2 + c) * 512];
        vdst[c] = &Vs[0][(w * 2 + c) * 512];
    }

    // ---- hoisted LDS read bases (st/df/sf-invariant) ----
    const int p = l15 & 7;                    // (row&7) for all frag rows: 16|row-l15
    const unsigned short* kfp0 = &Ks[0][0] + l15 * 64 + ((l4 ^ p) * 8);
    const unsigned short* kfp1 = &Ks[0][0] + l15 * 64 + (((4 + l4) ^ p) * 8);
    const unsigned short* vfp0 = &Vs[0][0] + l15 * 64 + ((((l4 >> 1) + 0) ^ p) * 8) + (l4 & 1) * 4;
    const unsigned short* vfp1 = &Vs[0][0] + l15 * 64 + ((((l4 >> 1) + 2) ^ p) * 8) + (l4 & 1) * 4;
    const unsigned short* vfp2 = &Vs[0][0] + l15 * 64 + ((((l4 >> 1) + 4) ^ p) * 8) + (l4 & 1) * 4;
    const unsigned short* vfp3 = &Vs[0][0] + l15 * 64 + ((((l4 >> 1) + 6) ^ p) * 8) + (l4 & 1) * 4;

    // Q B-fragment: col = q = l15 (wave rows t0 + w*16 + l15), k = d
    bf16x8 qf0, qf1;
    {
        const unsigned short* qp = qb + hb + (size_t)(t0 + w * 16 + l15) * 64 + l4 * 8;
        qf0 = *(const bf16x8*)(qp);
        qf1 = *(const bf16x8*)(qp + 32);
    }

    const f32x4 z = {0.f, 0.f, 0.f, 0.f};
    f32x4 acc[4];
#pragma unroll
    for (int i = 0; i < 4; ++i) acc[i] = z;
    float accd = 0.f;                        // denominator partial for q = l15

    const int wrow0 = t0 + w * 16;
    const int tq = wrow0 + l15;              // this lane's q row

    // prologue: stage tile 0 into buf 0 (4 loads per thread)
#pragma unroll
    for (int c = 0; c < 2; ++c) {
        gload_lds16(kgp[c], kdst[c]);
        gload_lds16(vgp[c], vdst[c]);
    }

    auto compute_tile = [&](int roff, int s0, bool mask) {
        // ---- swapped QK^T: sC[sf] rows = s (sf*16 + l4*4 + r), col = q = l15 ----
        const unsigned short* kc0 = kfp0 + roff;
        const unsigned short* kc1 = kfp1 + roff;
        f32x4 sC[4];
#pragma unroll
        for (int sf = 0; sf < 4; ++sf) {
            bf16x8 kf0 = *(const bf16x8*)(kc0 + sf * 1024);
            bf16x8 kf1 = *(const bf16x8*)(kc1 + sf * 1024);
            f32x4 c = z;
            c = __builtin_amdgcn_mfma_f32_16x16x32_bf16(kf0, qf0, c, 0, 0, 0);
            c = __builtin_amdgcn_mfma_f32_16x16x32_bf16(kf1, qf1, c, 0, 0, 0);
            sC[sf] = c;
        }
        // ---- YAT transform + (optional) causal mask + lane-local row-sum ----
        float part_ = 0.f;
#pragma unroll
        for (int sf = 0; sf < 4; ++sf)
#pragma unroll
            for (int r = 0; r < 4; ++r) {
                const float xd = sC[sf][r];
                const float den = __builtin_fmaf(-2.0f, xd, 2.01f);
                float Kv = xd * xd * __builtin_amdgcn_rcpf(den);
                if (mask) {
                    const int s = s0 + sf * 16 + l4 * 4 + r;
                    if (s > tq) Kv = 0.f;
                }
                part_ += Kv;
                sC[sf][r] = Kv;
            }
        accd += part_;
        // ---- pack A-frags: a0 = s 0..31, a1 = s 32..63 (slot order sigma) ----
        uint4 p0, p1;
        p0.x = cvtpk_bf16(sC[0][0], sC[0][1]);
        p0.y = cvtpk_bf16(sC[0][2], sC[0][3]);
        p0.z = cvtpk_bf16(sC[1][0], sC[1][1]);
        p0.w = cvtpk_bf16(sC[1][2], sC[1][3]);
        p1.x = cvtpk_bf16(sC[2][0], sC[2][1]);
        p1.y = cvtpk_bf16(sC[2][2], sC[2][3]);
        p1.z = cvtpk_bf16(sC[3][0], sC[3][1]);
        p1.w = cvtpk_bf16(sC[3][2], sC[3][3]);
        const bf16x8 a0 = __builtin_bit_cast(bf16x8, p0);
        const bf16x8 a1 = __builtin_bit_cast(bf16x8, p1);
        // ---- PV: B slot (l4,j) = V[sigma(l4,j)][d]; b64 reads, reg concat ----
        const unsigned short* vc0 = vfp0 + roff;
        const unsigned short* vc1 = vfp1 + roff;
        const unsigned short* vc2 = vfp2 + roff;
        const unsigned short* vc3 = vfp3 + roff;
#pragma unroll
        for (int df = 0; df < 4; ++df) {
            const uint2 u0 = *(const uint2*)(vc0 + df * 1024);
            const uint2 u1 = *(const uint2*)(vc1 + df * 1024);
            const uint2 u2 = *(const uint2*)(vc2 + df * 1024);
            const uint2 u3 = *(const uint2*)(vc3 + df * 1024);
            uint4 b0v, b1v;
            b0v.x = u0.x; b0v.y = u0.y; b0v.z = u1.x; b0v.w = u1.y;
            b1v.x = u2.x; b1v.y = u2.y; b1v.z = u3.x; b1v.w = u3.y;
            const bf16x8 B0 = __builtin_bit_cast(bf16x8, b0v);
            const bf16x8 B1 = __builtin_bit_cast(bf16x8, b1v);
            acc[df] = __builtin_amdgcn_mfma_f32_16x16x32_bf16(a0, B0, acc[df], 0, 0, 0);
            acc[df] = __builtin_amdgcn_mfma_f32_16x16x32_bf16(a1, B1, acc[df], 0, 0, 0);
        }
    };

    // interior steps: prefetch next tile, no causal mask
    for (int st = 0; st < t0i; ++st) {
        const int dsto = ((st & 1) ^ 1) * 4096;
#pragma unroll
        for (int c = 0; c < 2; ++c) {
            kgp[c] += 4096;   // next 64 s-rows
            vgp[c] += 64;     // next 64 t-cols
            gload_lds16(kgp[c], kdst[c] + dsto);
            gload_lds16(vgp[c], vdst[c] + dsto);
        }
        asm volatile("s_waitcnt vmcnt(4)" ::: "memory");
        __builtin_amdgcn_sched_barrier(0);
        __builtin_amdgcn_s_barrier();
        compute_tile((st & 1) * 4096, st * AT_TS, false);
        __builtin_amdgcn_sched_barrier(0);
        __builtin_amdgcn_s_barrier();
    }
    // final (diagonal) step: mask, no prefetch, no trailing barrier
    {
        asm volatile("s_waitcnt vmcnt(0)" ::: "memory");
        __builtin_amdgcn_sched_barrier(0);
        __builtin_amdgcn_s_barrier();
        compute_tile((t0i & 1) * 4096, t0i * AT_TS, true);
    }

    // denominator: reduce across l4 groups (disjoint s ranges), then fetch per-row
    accd += __shfl_xor(accd, 16);
    accd += __shfl_xor(accd, 32);

    const int b = bh >> 4, h = bh & 15;
#pragma unroll
    for (int r = 0; r < 4; ++r) {
        const float den = __shfl(accd, l4 * 4 + r) + 1e-6f;
#pragma unroll
        for (int df = 0; df < 4; ++df) {
            const int t = wrow0 + l4 * 4 + r;
            const float o = acc[df][r] / den;
            attnb[((size_t)b * T_SEQ + t) * D_MODEL + h * 64 + df * 16 + l15] = f2bf(o);
        }
    }
}

extern "C" void kernel_launch(void* const* d_in, const int* in_sizes, int n_in,
                              void* d_out, int out_size, void* d_ws, size_t ws_size,
                              hipStream_t stream) {
    const float* x    = (const float*)d_in[0];   // [2,2048,1024]
    const float* Wqkv = (const float*)d_in[1];   // [3072,1024]
    const float* Wout = (const float*)d_in[2];   // [1024,1024]
    float* out = (float*)d_out;                  // [2,2048,1024] fp32

    // Workspace overlay (58 MB):
    //  [0,8):    xb          [8,16):  wqkvb (6 used)
    //  [16,24):  vrow        [24,32): vbT
    //  [32,34):  woutb
    //  [34,42):  qb          [42,50): kb        [50,58): attnb
    char* ws = (char*)d_ws;
    unsigned short* xb    = (unsigned short*)(ws);
    unsigned short* wqkvb = (unsigned short*)(ws + (size_t)8 * 1024 * 1024);
    unsigned short* vrow  = (unsigned short*)(ws + (size_t)16 * 1024 * 1024);
    unsigned short* vbT   = (unsigned short*)(ws + (size_t)24 * 1024 * 1024);
    unsigned short* woutb = (unsigned short*)(ws + (size_t)32 * 1024 * 1024);
    unsigned short* qbp   = (unsigned short*)(ws + (size_t)34 * 1024 * 1024);
    unsigned short* kbp   = (unsigned short*)(ws + (size_t)42 * 1024 * 1024);
    unsigned short* attnb = (unsigned short*)(ws + (size_t)50 * 1024 * 1024);

    cvt_bf16_3<<<4096, 256, 0, stream>>>(x, xb, BT * D_MODEL / 8,
                                         Wqkv, wqkvb, QKV_N * D_MODEL / 8,
                                         Wout, woutb, D_MODEL * D_MODEL / 8);

    // QKV GEMM with fused L2-norm (q,k -> qbp/kbp) and v -> vrow
    gemm_bt_mfma<2><<<(QKV_N / 128) * (BT / 128), 256, 0, stream>>>(
        xb, wqkvb, vrow, qbp, kbp, BT, QKV_N, D_MODEL);

    v_cvt_T<<<dim3(T_SEQ / 64, 32), 256, 0, stream>>>(vrow, vbT);

    attn_mfma<<<1024, 256, 0, stream>>>(qbp, kbp, vbT, attnb);

    gemm_bt_mfma<0><<<(D_MODEL / 128) * (BT / 128), 256, 0, stream>>>(
        attnb, woutb, out, nullptr, nullptr, BT, D_MODEL, D_MODEL);
}

// Round 7
// 176.058 us; speedup vs baseline: 8.6381x; 1.0216x over previous
//
#include <hip/hip_runtime.h>
#include <hip/hip_bf16.h>

// B=2, T=2048, D=1024, H=16, hd=64
#define T_SEQ 2048
#define D_MODEL 1024
#define BT 4096
#define QKV_N 3072

typedef __attribute__((ext_vector_type(8))) short bf16x8;
typedef __attribute__((ext_vector_type(4))) short bf16x4;
typedef __attribute__((ext_vector_type(4))) float f32x4;

typedef unsigned int __attribute__((address_space(1))) as1_uint;
typedef unsigned int __attribute__((address_space(3))) as3_uint;

__device__ __forceinline__ unsigned short f2bf(float f) {
    unsigned u = __builtin_bit_cast(unsigned, f);
    u += 0x7fffu + ((u >> 16) & 1u);   // round-to-nearest-even
    return (unsigned short)(u >> 16);
}
__device__ __forceinline__ float bf2f(unsigned short h) {
    unsigned u = ((unsigned)h) << 16;
    return __builtin_bit_cast(float, u);
}
__device__ __forceinline__ void gload_lds16(const void* g, void* l) {
    __builtin_amdgcn_global_load_lds((const as1_uint*)g, (as3_uint*)l, 16, 0, 0);
}
__device__ __forceinline__ unsigned cvtpk_bf16(float lo, float hi) {
    unsigned r;
    asm("v_cvt_pk_bf16_f32 %0, %1, %2" : "=v"(r) : "v"(lo), "v"(hi));
    return r;
}

// ---------------- fp32 -> bf16 convert, all three tensors in one launch ------
__global__ __launch_bounds__(256) void cvt_bf16_3(const float* __restrict__ s0, unsigned short* __restrict__ d0, int n0,
                                                  const float* __restrict__ s1, unsigned short* __restrict__ d1, int n1,
                                                  const float* __restrict__ s2, unsigned short* __restrict__ d2, int n2) {
    int i = blockIdx.x * 256 + threadIdx.x;   // 8-element units
    const float* s; unsigned short* d;
    if (i < n0) { s = s0; d = d0; }
    else if (i < n0 + n1) { i -= n0; s = s1; d = d1; }
    else if (i < n0 + n1 + n2) { i -= n0 + n1; s = s2; d = d2; }
    else return;
    const float4* sp = (const float4*)s + (size_t)i * 2;
    const float4 a = sp[0], b = sp[1];
    uint4 o;
    o.x = (unsigned)f2bf(a.x) | ((unsigned)f2bf(a.y) << 16);
    o.y = (unsigned)f2bf(a.z) | ((unsigned)f2bf(a.w) << 16);
    o.z = (unsigned)f2bf(b.x) | ((unsigned)f2bf(b.y) << 16);
    o.w = (unsigned)f2bf(b.z) | ((unsigned)f2bf(b.w) << 16);
    ((uint4*)d)[i] = o;
}

// ---------------- MFMA GEMM: C[M,N] = A[M,K] @ B[N,K]^T (bf16 in, fp32 acc) ----
// m97 structure: 128x128 tile, BK=64, 4 waves, global_load_lds width 16,
// slot-XOR swizzle keyed on row&7. 1D grid, XCD-chunked decode.
// MODE 0: fp32 C write.  MODE 2: fused QKV epilogue — q/k waves L2-normalize
// their head (64 cols = one wave) and write bf16 to qb/kb [bh][t][64];
// v waves write bf16 to vrow [4096][1024].
template<int MODE>
__global__ __launch_bounds__(256) void gemm_bt_mfma(const unsigned short* __restrict__ A,
                                                    const unsigned short* __restrict__ B,
                                                    void* __restrict__ Cout,
                                                    unsigned short* __restrict__ qbp,
                                                    unsigned short* __restrict__ kbp,
                                                    int M, int N, int K) {
    __shared__ unsigned short As[128 * 64];
    __shared__ unsigned short Bs[128 * 64];
    const int tid = threadIdx.x;
    const int w = tid >> 6;
    const int l = tid & 63;
    const int l15 = l & 15, l4 = l >> 4;

    // XCD-chunked: each XCD gets a contiguous run of n-strips x 32 m-tiles
    const int nblocks = (M / 128) * (N / 128);
    const int cpx = nblocks >> 3;
    const int id2 = (blockIdx.x & 7) * cpx + (blockIdx.x >> 3);
    const int bm = (id2 & 31) * 128;
    const int bn = (id2 >> 5) * 128;

    const int wm = (w >> 1) * 64, wn = (w & 1) * 64;

    const f32x4 z = {0.f, 0.f, 0.f, 0.f};
    f32x4 acc[4][4];
#pragma unroll
    for (int m = 0; m < 4; ++m)
#pragma unroll
        for (int n = 0; n < 4; ++n) acc[m][n] = z;

    const int lrow = l >> 3;
    const int lslot = (l & 7) ^ (lrow & 7);   // pre-swizzled global source slot

    for (int k0 = 0; k0 < K; k0 += 64) {
#pragma unroll
        for (int i = 0; i < 4; ++i) {
            const int row = w * 32 + i * 8 + lrow;
            gload_lds16(A + (size_t)(bm + row) * K + k0 + lslot * 8, As + (w * 4 + i) * 512);
            gload_lds16(B + (size_t)(bn + row) * K + k0 + lslot * 8, Bs + (w * 4 + i) * 512);
        }
        __syncthreads();
        bf16x8 af[4][2], bfr[4][2];
#pragma unroll
        for (int m = 0; m < 4; ++m) {
            const int row = wm + m * 16 + l15;
            af[m][0] = *(const bf16x8*)(As + row * 64 + ((l4 ^ (row & 7)) * 8));
            af[m][1] = *(const bf16x8*)(As + row * 64 + (((4 + l4) ^ (row & 7)) * 8));
        }
#pragma unroll
        for (int n = 0; n < 4; ++n) {
            const int row = wn + n * 16 + l15;
            bfr[n][0] = *(const bf16x8*)(Bs + row * 64 + ((l4 ^ (row & 7)) * 8));
            bfr[n][1] = *(const bf16x8*)(Bs + row * 64 + (((4 + l4) ^ (row & 7)) * 8));
        }
#pragma unroll
        for (int m = 0; m < 4; ++m)
#pragma unroll
            for (int n = 0; n < 4; ++n) {
                acc[m][n] = __builtin_amdgcn_mfma_f32_16x16x32_bf16(af[m][0], bfr[n][0], acc[m][n], 0, 0, 0);
                acc[m][n] = __builtin_amdgcn_mfma_f32_16x16x32_bf16(af[m][1], bfr[n][1], acc[m][n], 0, 0, 0);
            }
        __syncthreads();
    }

    if (MODE == 0) {
#pragma unroll
        for (int m = 0; m < 4; ++m)
#pragma unroll
            for (int n = 0; n < 4; ++n)
#pragma unroll
                for (int r = 0; r < 4; ++r) {
                    const int row = bm + wm + m * 16 + l4 * 4 + r;
                    const int col = bn + wn + n * 16 + l15;
                    ((float*)Cout)[(size_t)row * N + col] = acc[m][n][r];
                }
    } else {
        // fused QKV epilogue. Wave's 64 cols = exactly one head of q, k or v.
        const int gcol0 = bn + wn;
        const int part = gcol0 >> 10;        // 0=q 1=k 2=v (wave-uniform)
        const int h = (gcol0 >> 6) & 15;
        if (part < 2) {
            unsigned short* dst = part ? kbp : qbp;
#pragma unroll
            for (int m = 0; m < 4; ++m)
#pragma unroll
                for (int r = 0; r < 4; ++r) {
                    float ss = 0.f;
#pragma unroll
                    for (int n = 0; n < 4; ++n) ss = fmaf(acc[m][n][r], acc[m][n][r], ss);
                    ss += __shfl_xor(ss, 1);
                    ss += __shfl_xor(ss, 2);
                    ss += __shfl_xor(ss, 4);
                    ss += __shfl_xor(ss, 8);
                    const float sc = 1.0f / fmaxf(sqrtf(ss), 1e-12f);
                    const int row = bm + wm + m * 16 + l4 * 4 + r;
                    const int bh2 = (row >> 11) * 16 + h;
                    unsigned short* pdst = dst + ((size_t)bh2 * T_SEQ + (row & 2047)) * 64 + l15;
#pragma unroll
                    for (int n = 0; n < 4; ++n) pdst[n * 16] = f2bf(acc[m][n][r] * sc);
                }
        } else {
            unsigned short* vrow = (unsigned short*)Cout;    // [4096][1024]
            const int vcol0 = gcol0 - 2048;
#pragma unroll
            for (int m = 0; m < 4; ++m)
#pragma unroll
                for (int n = 0; n < 4; ++n)
#pragma unroll
                    for (int r = 0; r < 4; ++r) {
                        const int row = bm + wm + m * 16 + l4 * 4 + r;
                        vrow[(size_t)row * D_MODEL + vcol0 + n * 16 + l15] = f2bf(acc[m][n][r]);
                    }
        }
    }
}

// ---------------- V relayout: vrow [b][t][h*64+d] -> vbT [b][h][d][t] --------
__global__ __launch_bounds__(256) void v_cvt_T(const unsigned short* __restrict__ vrow,
                                               unsigned short* __restrict__ vbT) {
    __shared__ unsigned short tile[64][72];  // [d][t]
    const int bh = blockIdx.y;
    const int b = bh >> 4, h = bh & 15;
    const int t0 = blockIdx.x * 64;
    const int r = threadIdx.x >> 2;          // t within tile
    const int c = (threadIdx.x & 3) * 16;    // d chunk
    const unsigned short* src = vrow + (size_t)(b * T_SEQ + t0 + r) * D_MODEL + h * 64 + c;
    uint4 v0 = *(const uint4*)(src);
    uint4 v1 = *(const uint4*)(src + 8);
    unsigned short tmp[16];
    *(uint4*)tmp = v0;
    *(uint4*)(tmp + 8) = v1;
#pragma unroll
    for (int j = 0; j < 16; ++j) tile[c + j][r] = tmp[j];
    __syncthreads();
    const int d = threadIdx.x >> 2;
    const int tc = (threadIdx.x & 3) * 16;
    unsigned short tmp2[16];
#pragma unroll
    for (int j = 0; j < 16; ++j) tmp2[j] = tile[d][tc + j];
    unsigned short* dst = vbT + ((size_t)bh * 64 + d) * T_SEQ + t0 + tc;
    *(uint4*)dst = *(uint4*)tmp2;
    *(uint4*)(dst + 8) = *(uint4*)(tmp2 + 8);
}

// ---------------- Causal YAT attention, MFMA, pipelined, swapped-QK ----------
// 4 waves/block, q-tile 64 (wave owns 16 rows), key tiles of 64, K/V^T
// double-buffered in LDS via global_load_lds + counted vmcnt. Swapped QK^T
// (mfma(K,Q)) + slot-permutation sigma on both PV operands: no S LDS
// round-trip, no cross-lane ops. All LDS read/staging addresses hoisted to
// registers. __launch_bounds__(256,4): cap 4 blocks/CU (= grid/CU), VGPR
// budget 128 so loop state stays resident (at (256) default the allocator
// targeted 8 waves/EU -> 56 VGPR -> remat storm, VALUBusy 53%).
#define AT_TS 64

__global__ __launch_bounds__(256, 4) void attn_mfma(const unsigned short* __restrict__ qb,
                                                    const unsigned short* __restrict__ kb,
                                                    const unsigned short* __restrict__ vbT,
                                                    unsigned short* __restrict__ attnb) {
    __shared__ unsigned short Ks[2][64 * 64];   // [buf][s-row][8 slots of 8], slot-swizzled
    __shared__ unsigned short Vs[2][64 * 64];   // [buf][d-row][8 slots], slot-swizzled

    const int tid = threadIdx.x;
    const int w = tid >> 6;
    const int l = tid & 63;
    const int l15 = l & 15, l4 = l >> 4;

    // XCD-chunked, longest-first: 4 heads per XCD, t0 descending
    const int id = blockIdx.x;               // 0..1023
    const int xcd = id & 7;
    const int within = id >> 3;              // 0..127
    const int bh = xcd * 4 + (within & 3);
    const int t0i = 31 - (within >> 2);      // 0..31
    const int t0 = t0i * 64;

    const size_t hb = (size_t)bh * T_SEQ * 64;

    // ---- staging pointers (advanced incrementally per step) ----
    const int lrow = l >> 3;
    const int lslot = (l & 7) ^ (lrow & 7);
    const unsigned short* kgp[2];
    const unsigned short* vgp[2];
    unsigned short* kdst[2];
    unsigned short* vdst[2];
#pragma unroll
    for (int c = 0; c < 2; ++c) {
        const int row = w * 16 + c * 8 + lrow;
        kgp[c] = kb + hb + (size_t)row * 64 + lslot * 8;
        vgp[c] = vbT + hb + (size_t)row * T_SEQ + lslot * 8;
        kdst[c] = &Ks[0][(w * 2 + c) * 512];
        vdst[c] = &Vs[0][(w * 2 + c) * 512];
    }

    // ---- hoisted LDS read bases (st/df/sf-invariant) ----
    const int p = l15 & 7;                    // (row&7) for all frag rows: 16|row-l15
    const unsigned short* kfp0 = &Ks[0][0] + l15 * 64 + ((l4 ^ p) * 8);
    const unsigned short* kfp1 = &Ks[0][0] + l15 * 64 + (((4 + l4) ^ p) * 8);
    const unsigned short* vfp0 = &Vs[0][0] + l15 * 64 + ((((l4 >> 1) + 0) ^ p) * 8) + (l4 & 1) * 4;
    const unsigned short* vfp1 = &Vs[0][0] + l15 * 64 + ((((l4 >> 1) + 2) ^ p) * 8) + (l4 & 1) * 4;
    const unsigned short* vfp2 = &Vs[0][0] + l15 * 64 + ((((l4 >> 1) + 4) ^ p) * 8) + (l4 & 1) * 4;
    const unsigned short* vfp3 = &Vs[0][0] + l15 * 64 + ((((l4 >> 1) + 6) ^ p) * 8) + (l4 & 1) * 4;

    // Q B-fragment: col = q = l15 (wave rows t0 + w*16 + l15), k = d
    bf16x8 qf0, qf1;
    {
        const unsigned short* qp = qb + hb + (size_t)(t0 + w * 16 + l15) * 64 + l4 * 8;
        qf0 = *(const bf16x8*)(qp);
        qf1 = *(const bf16x8*)(qp + 32);
    }

    const f32x4 z = {0.f, 0.f, 0.f, 0.f};
    f32x4 acc[4];
#pragma unroll
    for (int i = 0; i < 4; ++i) acc[i] = z;
    float accd = 0.f;                        // denominator partial for q = l15

    const int wrow0 = t0 + w * 16;
    const int tq = wrow0 + l15;              // this lane's q row

    // prologue: stage tile 0 into buf 0 (4 loads per thread)
#pragma unroll
    for (int c = 0; c < 2; ++c) {
        gload_lds16(kgp[c], kdst[c]);
        gload_lds16(vgp[c], vdst[c]);
    }

    auto compute_tile = [&](int roff, int s0, bool mask) {
        // ---- swapped QK^T: sC[sf] rows = s (sf*16 + l4*4 + r), col = q = l15 ----
        const unsigned short* kc0 = kfp0 + roff;
        const unsigned short* kc1 = kfp1 + roff;
        f32x4 sC[4];
        __builtin_amdgcn_s_setprio(1);
#pragma unroll
        for (int sf = 0; sf < 4; ++sf) {
            bf16x8 kf0 = *(const bf16x8*)(kc0 + sf * 1024);
            bf16x8 kf1 = *(const bf16x8*)(kc1 + sf * 1024);
            f32x4 c = z;
            c = __builtin_amdgcn_mfma_f32_16x16x32_bf16(kf0, qf0, c, 0, 0, 0);
            c = __builtin_amdgcn_mfma_f32_16x16x32_bf16(kf1, qf1, c, 0, 0, 0);
            sC[sf] = c;
        }
        __builtin_amdgcn_s_setprio(0);
        // ---- YAT transform + (optional) causal mask + lane-local row-sum ----
        float part_ = 0.f;
#pragma unroll
        for (int sf = 0; sf < 4; ++sf)
#pragma unroll
            for (int r = 0; r < 4; ++r) {
                const float xd = sC[sf][r];
                const float den = __builtin_fmaf(-2.0f, xd, 2.01f);
                float Kv = xd * xd * __builtin_amdgcn_rcpf(den);
                if (mask) {
                    const int s = s0 + sf * 16 + l4 * 4 + r;
                    if (s > tq) Kv = 0.f;
                }
                part_ += Kv;
                sC[sf][r] = Kv;
            }
        accd += part_;
        // ---- pack A-frags: a0 = s 0..31, a1 = s 32..63 (slot order sigma) ----
        uint4 p0, p1;
        p0.x = cvtpk_bf16(sC[0][0], sC[0][1]);
        p0.y = cvtpk_bf16(sC[0][2], sC[0][3]);
        p0.z = cvtpk_bf16(sC[1][0], sC[1][1]);
        p0.w = cvtpk_bf16(sC[1][2], sC[1][3]);
        p1.x = cvtpk_bf16(sC[2][0], sC[2][1]);
        p1.y = cvtpk_bf16(sC[2][2], sC[2][3]);
        p1.z = cvtpk_bf16(sC[3][0], sC[3][1]);
        p1.w = cvtpk_bf16(sC[3][2], sC[3][3]);
        const bf16x8 a0 = __builtin_bit_cast(bf16x8, p0);
        const bf16x8 a1 = __builtin_bit_cast(bf16x8, p1);
        // ---- PV: B slot (l4,j) = V[sigma(l4,j)][d]; b64 reads, reg concat ----
        const unsigned short* vc0 = vfp0 + roff;
        const unsigned short* vc1 = vfp1 + roff;
        const unsigned short* vc2 = vfp2 + roff;
        const unsigned short* vc3 = vfp3 + roff;
        __builtin_amdgcn_s_setprio(1);
#pragma unroll
        for (int df = 0; df < 4; ++df) {
            const uint2 u0 = *(const uint2*)(vc0 + df * 1024);
            const uint2 u1 = *(const uint2*)(vc1 + df * 1024);
            const uint2 u2 = *(const uint2*)(vc2 + df * 1024);
            const uint2 u3 = *(const uint2*)(vc3 + df * 1024);
            uint4 b0v, b1v;
            b0v.x = u0.x; b0v.y = u0.y; b0v.z = u1.x; b0v.w = u1.y;
            b1v.x = u2.x; b1v.y = u2.y; b1v.z = u3.x; b1v.w = u3.y;
            const bf16x8 B0 = __builtin_bit_cast(bf16x8, b0v);
            const bf16x8 B1 = __builtin_bit_cast(bf16x8, b1v);
            acc[df] = __builtin_amdgcn_mfma_f32_16x16x32_bf16(a0, B0, acc[df], 0, 0, 0);
            acc[df] = __builtin_amdgcn_mfma_f32_16x16x32_bf16(a1, B1, acc[df], 0, 0, 0);
        }
        __builtin_amdgcn_s_setprio(0);
    };

    // interior steps: prefetch next tile, no causal mask
    for (int st = 0; st < t0i; ++st) {
        const int dsto = ((st & 1) ^ 1) * 4096;
#pragma unroll
        for (int c = 0; c < 2; ++c) {
            kgp[c] += 4096;   // next 64 s-rows
            vgp[c] += 64;     // next 64 t-cols
            gload_lds16(kgp[c], kdst[c] + dsto);
            gload_lds16(vgp[c], vdst[c] + dsto);
        }
        asm volatile("s_waitcnt vmcnt(4)" ::: "memory");
        __builtin_amdgcn_sched_barrier(0);
        __builtin_amdgcn_s_barrier();
        compute_tile((st & 1) * 4096, st * AT_TS, false);
        __builtin_amdgcn_sched_barrier(0);
        __builtin_amdgcn_s_barrier();
    }
    // final (diagonal) step: mask, no prefetch, no trailing barrier
    {
        asm volatile("s_waitcnt vmcnt(0)" ::: "memory");
        __builtin_amdgcn_sched_barrier(0);
        __builtin_amdgcn_s_barrier();
        compute_tile((t0i & 1) * 4096, t0i * AT_TS, true);
    }

    // denominator: reduce across l4 groups (disjoint s ranges), then fetch per-row
    accd += __shfl_xor(accd, 16);
    accd += __shfl_xor(accd, 32);

    const int b = bh >> 4, h = bh & 15;
#pragma unroll
    for (int r = 0; r < 4; ++r) {
        const float den = __shfl(accd, l4 * 4 + r) + 1e-6f;
#pragma unroll
        for (int df = 0; df < 4; ++df) {
            const int t = wrow0 + l4 * 4 + r;
            const float o = acc[df][r] / den;
            attnb[((size_t)b * T_SEQ + t) * D_MODEL + h * 64 + df * 16 + l15] = f2bf(o);
        }
    }
}

extern "C" void kernel_launch(void* const* d_in, const int* in_sizes, int n_in,
                              void* d_out, int out_size, void* d_ws, size_t ws_size,
                              hipStream_t stream) {
    const float* x    = (const float*)d_in[0];   // [2,2048,1024]
    const float* Wqkv = (const float*)d_in[1];   // [3072,1024]
    const float* Wout = (const float*)d_in[2];   // [1024,1024]
    float* out = (float*)d_out;                  // [2,2048,1024] fp32

    // Workspace overlay (58 MB):
    //  [0,8):    xb          [8,16):  wqkvb (6 used)
    //  [16,24):  vrow        [24,32): vbT
    //  [32,34):  woutb
    //  [34,42):  qb          [42,50): kb        [50,58): attnb
    char* ws = (char*)d_ws;
    unsigned short* xb    = (unsigned short*)(ws);
    unsigned short* wqkvb = (unsigned short*)(ws + (size_t)8 * 1024 * 1024);
    unsigned short* vrow  = (unsigned short*)(ws + (size_t)16 * 1024 * 1024);
    unsigned short* vbT   = (unsigned short*)(ws + (size_t)24 * 1024 * 1024);
    unsigned short* woutb = (unsigned short*)(ws + (size_t)32 * 1024 * 1024);
    unsigned short* qbp   = (unsigned short*)(ws + (size_t)34 * 1024 * 1024);
    unsigned short* kbp   = (unsigned short*)(ws + (size_t)42 * 1024 * 1024);
    unsigned short* attnb = (unsigned short*)(ws + (size_t)50 * 1024 * 1024);

    cvt_bf16_3<<<4096, 256, 0, stream>>>(x, xb, BT * D_MODEL / 8,
                                         Wqkv, wqkvb, QKV_N * D_MODEL / 8,
                                         Wout, woutb, D_MODEL * D_MODEL / 8);

    // QKV GEMM with fused L2-norm (q,k -> qbp/kbp) and v -> vrow
    gemm_bt_mfma<2><<<(QKV_N / 128) * (BT / 128), 256, 0, stream>>>(
        xb, wqkvb, vrow, qbp, kbp, BT, QKV_N, D_MODEL);

    v_cvt_T<<<dim3(T_SEQ / 64, 32), 256, 0, stream>>>(vrow, vbT);

    attn_mfma<<<1024, 256, 0, stream>>>(qbp, kbp, vbT, attnb);

    gemm_bt_mfma<0><<<(D_MODEL / 128) * (BT / 128), 256, 0, stream>>>(
        attnb, woutb, out, nullptr, nullptr, BT, D_MODEL, D_MODEL);
}